// Round 6
// baseline (2971.583 us; speedup 1.0000x reference)
//
#include <hip/hip_runtime.h>
#include <cstdint>
#include <cstddef>

// ---------------------------------------------------------------------------
// MambaFusion. R14 (on R13):
// R13 post-mortem: no dominant dispatch left (all <41us); budget says scans +
// dt path carry the most removable traffic. R14:
// - dt round-trip eliminated: x_proj writes fp32 [dt_r|B|C] rows (stride 64);
//   dt_proj kernel DELETED; scan p1/p3 compute dt = softplus(dt_r.dtw + dtb)
//   inline (dtw staged in LDS [256][25], conflict-free; dt_r row broadcast).
//   Saves ~70MB/call of dt write+2x read, one launch per call.
// - conv: 8-t sliding window (11 loads -> 8 outputs; read-amp 1.75->1.375).
// Workspace: 56.45M floats = 225.8 MB.
// ---------------------------------------------------------------------------

constexpr int BZv = 16, SEQ = 5, NV = 1;
constexpr int C = 384, DSTATE = 16, DCONV = 4, NLAYER = 4;
constexpr int DI = 768;
constexpr int DTR = 24;
constexpr int NTOK = (NV + 2) * SEQ * 64;  // 960
constexpr int T = NTOK + 2;                // 962
constexpr int M = BZv * T;                 // 15392
constexpr int HB = 8;                      // batches per half
constexpr int MH = HB * T;                 // 7696 rows per half
constexpr int XZdim = 2 * DI;              // 1536
constexpr int ND = DTR + 2 * DSTATE;       // 56
constexpr int NCHUNK = 26, TC = 37;        // 26*37 == 962
constexpr int NQ8 = 121;                   // ceil(T/8) 8-t quads
constexpr size_t SEC_SZ = (size_t)BZv * SEQ * C * 64;

// swizzled weight set sizes (elements per (layer[,dir]) set)
constexpr size_t SET1 = (size_t)C * C;        // 147,456 (fc)
constexpr size_t SETI = (size_t)2 * DI * C;   // 589,824 (in_proj)
constexpr size_t SETO = (size_t)C * DI;       // 294,912 (out_proj)
constexpr size_t SETX = (size_t)64 * DI;      // 49,152  (x_proj, N pad 56->64)
constexpr size_t WSZ1 = 4 * SET1;             // 589,824
constexpr size_t WSZI = 8 * SETI;             // 4,718,592
constexpr size_t WSZO = 8 * SETO;             // 2,359,296
constexpr size_t WSZX = 8 * SETX;             // 393,216

typedef __attribute__((ext_vector_type(8))) short short8;
typedef __attribute__((ext_vector_type(4))) float floatx4;

#define GLOAD_LDS16(g, l)                                        \
  __builtin_amdgcn_global_load_lds(                              \
      (const __attribute__((address_space(1))) void*)(g),        \
      (__attribute__((address_space(3))) void*)(l), 16, 0, 0)

__device__ __forceinline__ void split_bf16(float v, short& hi, short& lo) {
  unsigned u = __float_as_uint(v);
  unsigned hib = u & 0xFFFF0000u;      // truncate to bf16
  float r = v - __uint_as_float(hib);  // exact residual
  hi = (short)(hib >> 16);
  lo = (short)(__float_as_uint(r) >> 16);
}

__device__ __forceinline__ float join_bf16(short h, short l) {
  return __uint_as_float((unsigned)(unsigned short)h << 16) +
         __uint_as_float((unsigned)(unsigned short)l << 16);
}

// e[s] = e1^(s+1), 15 muls, ~4 deep.
__device__ __forceinline__ void pow16(float e1, float* e) {
  e[0] = e1;
  e[1] = e1 * e1;
  e[3] = e[1] * e[1];
  e[7] = e[3] * e[3];
  e[15] = e[7] * e[7];
  e[2] = e[1] * e[0];
  e[4] = e[3] * e[0];
  e[5] = e[3] * e[1];
  e[6] = e[5] * e[0];
  e[8] = e[7] * e[0];
  e[9] = e[7] * e[1];
  e[10] = e[9] * e[0];
  e[11] = e[7] * e[3];
  e[12] = e[11] * e[0];
  e[13] = e[11] * e[1];
  e[14] = e[13] * e[0];
}

// ------------------------------ token assembly -----------------------------
__global__ __launch_bounds__(256) void assemble_t_k(
    const float* __restrict__ img, const float* __restrict__ lid,
    const float* __restrict__ rad, const float* __restrict__ gps,
    const float* __restrict__ pe, float* __restrict__ x) {
  __shared__ float lds[64][129];
  int blk = blockIdx.x, tid = threadIdx.x;
  if (blk < 720) {
    int b = blk / 45;
    int rem = blk % 45;
    int g_ = rem / 3, cc = rem % 3;
    int sec = g_ / 5, s = g_ % 5;
    int srow = b * 5 + s;
    int which = (cc + sec) % 3;
    const float* src = (which == 0) ? img : (which == 1 ? lid : rad);
    const float* sp = src + (size_t)srow * (C * 64) + cc * 8192;
#pragma unroll
    for (int i = 0; i < 32; i++) {
      int lin = tid + 256 * i;
      lds[lin & 63][lin >> 6] = sp[lin];
    }
    __syncthreads();
#pragma unroll
    for (int i = 0; i < 32; i++) {
      int lin = tid + 256 * i;
      int p = lin >> 7, c = lin & 127;
      int t = g_ * 64 + p;
      int ccc = cc * 128 + c;
      x[((size_t)b * T + t) * C + ccc] = lds[p][c] + pe[(size_t)t * C + ccc];
    }
  } else {
#pragma unroll
    for (int i = 0; i < 48; i++) {
      int lin = tid + 256 * i;
      int r = lin / C, c = lin % C;
      int b = r >> 1, e = r & 1;
      x[((size_t)b * T + NTOK + e) * C + c] =
          gps[((size_t)b * 2 + e) * C + c] + pe[(size_t)(NTOK + e) * C + c];
    }
  }
}

// -------------------- fused LN (stats + apply -> planes) -------------------
__global__ __launch_bounds__(256) void ln_fused_k(
    const float* __restrict__ x, const float* __restrict__ g,
    const float* __restrict__ b, short* __restrict__ oh,
    short* __restrict__ ol) {
  int row = blockIdx.x * 4 + (threadIdx.x >> 6);
  int lane = threadIdx.x & 63;
  const float* xr = x + (size_t)row * C;
  float v[6];
  float s = 0.f;
#pragma unroll
  for (int j = 0; j < 6; j++) {
    v[j] = xr[lane + 64 * j];
    s += v[j];
  }
#pragma unroll
  for (int o = 32; o > 0; o >>= 1) s += __shfl_xor(s, o, 64);
  float mean = s * (1.f / 384.f);
  float q = 0.f;
#pragma unroll
  for (int j = 0; j < 6; j++) {
    float d = v[j] - mean;
    q += d * d;
  }
#pragma unroll
  for (int o = 32; o > 0; o >>= 1) q += __shfl_xor(q, o, 64);
  float rstd = rsqrtf(q * (1.f / 384.f) + 1e-5f);
#pragma unroll
  for (int j = 0; j < 6; j++) {
    int c = lane + 64 * j;
    float val = (v[j] - mean) * rstd * g[c] + b[c];
    short h, l;
    split_bf16(val, h, l);
    oh[(size_t)row * C + c] = h;
    ol[(size_t)row * C + c] = l;
  }
}

// ------------------------- LN row stats (final LN) -------------------------
__global__ __launch_bounds__(256) void ln_stats2_k(const float* __restrict__ x,
                                                   float* __restrict__ stats) {
  int row = blockIdx.x * 4 + (threadIdx.x >> 6);
  int lane = threadIdx.x & 63;
  const float* xr = x + (size_t)row * C;
  float v[6];
  float s = 0.f;
#pragma unroll
  for (int j = 0; j < 6; j++) {
    v[j] = xr[lane + 64 * j];
    s += v[j];
  }
#pragma unroll
  for (int o = 32; o > 0; o >>= 1) s += __shfl_xor(s, o, 64);
  float mean = s * (1.f / 384.f);
  float q = 0.f;
#pragma unroll
  for (int j = 0; j < 6; j++) {
    float d = v[j] - mean;
    q += d * d;
  }
#pragma unroll
  for (int o = 32; o > 0; o >>= 1) q += __shfl_xor(q, o, 64);
  if (lane == 0) {
    stats[2 * row] = mean;
    stats[2 * row + 1] = rsqrtf(q * (1.f / 384.f) + 1e-5f);
  }
}

// ------------------ weight cast to swizzled fragment order -----------------
// Output layout per set: idx = ((nf*KS + ks)*64 + lane)*8 + e, holding
// W[n = nf*16 + (lane&15)][k = ks*32 + (lane>>4)*8 + e], zero-padded when
// n >= NSRC or k >= KSRC. grid: (NP*KS*32/256, nsets).
template <int NSRC, int KSRC, int KS>
__global__ __launch_bounds__(256) void cast_swz_k(const float* __restrict__ src,
                                                  short* __restrict__ oh,
                                                  short* __restrict__ ol) {
  constexpr int NP = (NSRC + 15) & ~15;
  constexpr size_t SETSZ = (size_t)NP * KS * 32;
  int set = blockIdx.y;
  size_t idx = (size_t)blockIdx.x * 256 + threadIdx.x;
  int e = (int)(idx & 7);
  int lane = (int)((idx >> 3) & 63);
  size_t rest = idx >> 9;
  int ks = (int)(rest % KS);
  int nf = (int)(rest / KS);
  int n = nf * 16 + (lane & 15);
  int k = ks * 32 + ((lane >> 4) << 3) + e;
  float v = 0.f;
  if (n < NSRC && k < KSRC)
    v = src[(size_t)set * NSRC * KSRC + (size_t)n * KSRC + k];
  short h, l;
  split_bf16(v, h, l);
  oh[(size_t)set * SETSZ + idx] = h;
  ol[(size_t)set * SETSZ + idx] = l;
}

// ------------------ split-bf16 MFMA GEMM (128x128, B-direct) ---------------
// ACT: 0 none, 1 lrelu(0.2).
// OSPLIT: write hi/lo planes (stride N). W in swizzled fragment order.
// SWAPXY: m-tiles on blockIdx.x. XSWZ: flat 1-D grid, XCD-chunked decode
// (xcd = f%8 owns m-tiles [xcd*mpx, (xcd+1)*mpx), n fastest within).
template <int ACT, bool BIAS, bool FLIPA, bool OSPLIT, bool SWAPXY, bool XSWZ>
__global__ __launch_bounds__(256) void mgemm_k(
    const short* __restrict__ Ah, const short* __restrict__ Al, int K,
    const short* __restrict__ Wh, const short* __restrict__ Wl, int N,
    const float* __restrict__ bias, float* __restrict__ Co, int ldc,
    short* __restrict__ Oh, short* __restrict__ Ol, int Mrows, int arow_off,
    int crow_off, int nt, int mpx) {
  __shared__ __align__(16) short sAh[128 * 32];
  __shared__ __align__(16) short sAl[128 * 32];
  const int tid = threadIdx.x;
  const int wave = tid >> 6, lane = tid & 63;
  int bm_, bn_;
  if constexpr (XSWZ) {
    const int f = blockIdx.x;
    const int xcd = f & 7, j = f >> 3;
    bn_ = j % nt;
    bm_ = xcd * mpx + j / nt;
  } else {
    bm_ = SWAPXY ? blockIdx.x : blockIdx.y;
    bn_ = SWAPXY ? blockIdx.y : blockIdx.x;
  }
  const int m0 = bm_ * 128, n0 = bn_ * 128;
  const int lrow = lane >> 2, lchunk = lane & 3;
  const int wm = (wave >> 1) * 64, wn = (wave & 1) * 64;
  const int frow = lane & 15, fquad = lane >> 4;
  const int KST = K >> 5;
  const int nfb = (n0 + wn) >> 4;

  size_t arow[2];
#pragma unroll
  for (int p = 0; p < 2; p++) {
    int r = p * 64 + wave * 16 + lrow;
    int lm = m0 + r;
    if (lm >= Mrows) lm = Mrows - 1;
    int g = arow_off + lm;
    if (FLIPA) {
      int bb = g / T;
      int tt = g - bb * T;
      g = bb * T + (T - 1 - tt);
    }
    arow[p] = (size_t)g * K;
  }

  floatx4 acc[4][4] = {};
  for (int k0 = 0; k0 < K; k0 += 32) {
    if (k0) __syncthreads();
    const int kc = k0 + lchunk * 8;
#pragma unroll
    for (int p = 0; p < 2; p++) {
      GLOAD_LDS16(Ah + arow[p] + kc, &sAh[(p * 64 + wave * 16) * 32]);
      GLOAD_LDS16(Al + arow[p] + kc, &sAl[(p * 64 + wave * 16) * 32]);
    }
    const int ks = k0 >> 5;
    short8 bh[4], bl[4];
#pragma unroll
    for (int j = 0; j < 4; j++) {
      size_t bo = (((size_t)(nfb + j) * KST + ks) * 64 + lane) * 8;
      bh[j] = *(const short8*)&Wh[bo];
      bl[j] = *(const short8*)&Wl[bo];
    }
    __syncthreads();
    short8 ah[4], al[4];
#pragma unroll
    for (int i = 0; i < 4; i++) {
      int ra = (wm + i * 16 + frow) * 32 + fquad * 8;
      ah[i] = *(const short8*)&sAh[ra];
      al[i] = *(const short8*)&sAl[ra];
    }
#pragma unroll
    for (int i = 0; i < 4; i++)
#pragma unroll
      for (int j = 0; j < 4; j++) {
        acc[i][j] = __builtin_amdgcn_mfma_f32_16x16x32_bf16(ah[i], bh[j],
                                                            acc[i][j], 0, 0, 0);
        acc[i][j] = __builtin_amdgcn_mfma_f32_16x16x32_bf16(al[i], bh[j],
                                                            acc[i][j], 0, 0, 0);
        acc[i][j] = __builtin_amdgcn_mfma_f32_16x16x32_bf16(ah[i], bl[j],
                                                            acc[i][j], 0, 0, 0);
      }
  }
#pragma unroll
  for (int i = 0; i < 4; i++) {
#pragma unroll
    for (int r = 0; r < 4; r++) {
      int gm = m0 + wm + i * 16 + fquad * 4 + r;
      if (gm >= Mrows) continue;
      int grow = crow_off + gm;
#pragma unroll
      for (int j = 0; j < 4; j++) {
        int gn = n0 + wn + j * 16 + frow;
        if (gn >= N) continue;
        float v = acc[i][j][r];
        if constexpr (BIAS) v += bias[gn];
        if constexpr (ACT == 1) v = v >= 0.f ? v : 0.2f * v;
        if constexpr (OSPLIT) {
          short h, l;
          split_bf16(v, h, l);
          Oh[(size_t)grow * N + gn] = h;
          Ol[(size_t)grow * N + gn] = l;
        } else {
          Co[(size_t)grow * ldc + gn] = v;
        }
      }
    }
  }
}

// ------------------- split-bf16 MFMA GEMM (MTx64, B-direct) ----------------
// fp32 Co output, stride ldc, cols gn < N.
// ACT: 0 none, 4 combine v = e2*(e1 + v) (stride ldc).
// MT: m-tile rows. XSWZ: flat grid, XCD-chunked decode (see mgemm_k).
template <int ACT, bool BIAS, int MT = 64, bool XSWZ = false>
__global__ __launch_bounds__(256) void mgemm64_k(
    const short* __restrict__ Ah, const short* __restrict__ Al, int lda, int K,
    const short* __restrict__ Wh, const short* __restrict__ Wl, int N,
    const float* __restrict__ bias, float* __restrict__ Co, int ldc,
    const float* __restrict__ e1, const float* __restrict__ e2, int Mrows,
    int crow_off, int nt, int mpx) {
  __shared__ __align__(16) short sAh[MT * 32];
  __shared__ __align__(16) short sAl[MT * 32];
  const int tid = threadIdx.x;
  const int wave = tid >> 6, lane = tid & 63;
  int bm_, bn_;
  if constexpr (XSWZ) {
    const int f = blockIdx.x;
    const int xcd = f & 7, j = f >> 3;
    bn_ = j % nt;
    bm_ = xcd * mpx + j / nt;
  } else {
    bm_ = blockIdx.y;
    bn_ = blockIdx.x;
  }
  const int m0 = bm_ * MT, n0 = bn_ * 64;
  const int schunk = tid & 3;
  const int frow = lane & 15, fquad = lane >> 4;
  const int KST = K >> 5;
  const int nfw = (n0 >> 4) + wave;

  int lm = m0 + ((MT == 64) ? (tid >> 2) : (lane >> 2));
  if (lm >= Mrows) lm = Mrows - 1;
  size_t aoff = (size_t)lm * lda;

  floatx4 acc[MT / 16] = {};
  for (int k0 = 0; k0 < K; k0 += 32) {
    if (k0) __syncthreads();
    const int kc = k0 + schunk * 8;
    if constexpr (MT == 64) {
      GLOAD_LDS16(Ah + aoff + kc, &sAh[(wave * 16) * 32]);
      GLOAD_LDS16(Al + aoff + kc, &sAl[(wave * 16) * 32]);
    } else {
      if (wave == 0) GLOAD_LDS16(Ah + aoff + kc, &sAh[0]);
      if (wave == 1) GLOAD_LDS16(Al + aoff + kc, &sAl[0]);
    }
    const int ks = k0 >> 5;
    short8 bh, bl;
    {
      size_t bo = (((size_t)nfw * KST + ks) * 64 + lane) * 8;
      bh = *(const short8*)&Wh[bo];
      bl = *(const short8*)&Wl[bo];
    }
    __syncthreads();
    short8 ah[MT / 16], al[MT / 16];
#pragma unroll
    for (int i = 0; i < MT / 16; i++) {
      int ra = (i * 16 + frow) * 32 + fquad * 8;
      ah[i] = *(const short8*)&sAh[ra];
      al[i] = *(const short8*)&sAl[ra];
    }
#pragma unroll
    for (int i = 0; i < MT / 16; i++) {
      acc[i] = __builtin_amdgcn_mfma_f32_16x16x32_bf16(ah[i], bh, acc[i], 0, 0, 0);
      acc[i] = __builtin_amdgcn_mfma_f32_16x16x32_bf16(al[i], bh, acc[i], 0, 0, 0);
      acc[i] = __builtin_amdgcn_mfma_f32_16x16x32_bf16(ah[i], bl, acc[i], 0, 0, 0);
    }
  }
  const int gn = n0 + wave * 16 + frow;
  if (gn < N) {
#pragma unroll
    for (int i = 0; i < MT / 16; i++) {
#pragma unroll
      for (int r = 0; r < 4; r++) {
        int gm = m0 + i * 16 + fquad * 4 + r;
        if (gm >= Mrows) continue;
        int grow = crow_off + gm;
        float v = acc[i][r];
        if constexpr (BIAS) v += bias[gn];
        if constexpr (ACT == 4) {
          size_t o = (size_t)grow * ldc + gn;
          v = e2[o] * (e1[o] + v);
        }
        Co[(size_t)grow * ldc + gn] = v;
      }
    }
  }
}

// --------------------------- depthwise conv + silu -------------------------
// 8-t sliding-window: thread per (b, 8t-quad, d-pair); 11 row-loads ->
// 8 outputs from registers (amp 1.375). Emits xc bf16 hi/lo planes.
__global__ __launch_bounds__(256) void conv_k(const float* __restrict__ xz,
                                              const float* __restrict__ cw,
                                              const float* __restrict__ cb,
                                              short* __restrict__ xch,
                                              short* __restrict__ xcl) {
  int idx = blockIdx.x * 256 + threadIdx.x;  // [0, HB*NQ8*384)
  int dh = idx % (DI / 2);
  int rem = idx / (DI / 2);
  int q = rem % NQ8;
  int b = rem / NQ8;
  int d = dh * 2;
  int t0 = q * 8;
  const float* base = xz + (size_t)b * T * XZdim + d;
  float4 cwa = *(const float4*)&cw[d * 4];
  float4 cwb = *(const float4*)&cw[(d + 1) * 4];
  float cb0 = cb[d], cb1 = cb[d + 1];
  float2 w[11];
#pragma unroll
  for (int j = 0; j < 11; j++) {
    int tt = t0 - 3 + j;
    w[j] = (tt >= 0 && tt < T) ? *(const float2*)(base + (size_t)tt * XZdim)
                               : make_float2(0.f, 0.f);
  }
  const float cwx[4] = {cwa.x, cwa.y, cwa.z, cwa.w};
  const float cwy[4] = {cwb.x, cwb.y, cwb.z, cwb.w};
#pragma unroll
  for (int r = 0; r < 8; r++) {
    int t = t0 + r;
    if (t >= T) break;
    float a0 = cb0, a1 = cb1;
#pragma unroll
    for (int j = 0; j < 4; j++) {
      a0 += w[r + j].x * cwx[j];
      a1 += w[r + j].y * cwy[j];
    }
    float v0 = a0 / (1.f + __expf(-a0));
    float v1 = a1 / (1.f + __expf(-a1));
    short h0, l0, h1, l1;
    split_bf16(v0, h0, l0);
    split_bf16(v1, h1, l1);
    size_t o = ((size_t)b * T + t) * DI + d;
    *(short2*)&xch[o] = make_short2(h0, h1);
    *(short2*)&xcl[o] = make_short2(l0, l1);
  }
}

// ----------------------- chunked selective scan ----------------------------
// dt computed inline: dt = softplus(dt_r . dtw_d + dtb_d); dt_r from the
// fp32 xdbc row (cols 0..23, broadcast), dtw staged per-block in LDS.
// xdbc row layout (stride 64): [dt_r(24) | B(16) | C(16)].

// Phase 1: local scan from h=0; stores h_local[16] + sum(dt) per (b,ch,d).
__global__ __launch_bounds__(256) void scan_p1_k(
    const short* __restrict__ xch, const short* __restrict__ xcl,
    const float* __restrict__ xdbc, const float* __restrict__ dtw,
    const float* __restrict__ dtb, const float* __restrict__ alog,
    float* __restrict__ hchk, float* __restrict__ sdt) {
  __shared__ float sw[256][25];
  __shared__ float sb[256];
  int tid = threadIdx.x;
  int d = blockIdx.x * 256 + tid;
  int ch = blockIdx.y, b = blockIdx.z;
  {
    const float* src = dtw + (size_t)blockIdx.x * 256 * DTR;
    for (int idx = tid; idx < 256 * DTR; idx += 256)
      sw[idx / DTR][idx % DTR] = src[idx];
    sb[tid] = dtb[d];
  }
  __syncthreads();
  float A[DSTATE], h[DSTATE];
  bool powA = true;
#pragma unroll
  for (int s = 0; s < DSTATE; s++) {
    A[s] = -expf(alog[d * DSTATE + s]);
    powA = powA && (fabsf(A[s] + (float)(s + 1)) <= 1e-4f * (float)(s + 1));
    h[s] = 0.f;
  }
  const int t0 = ch * TC;
  const short* xchr = xch + ((size_t)b * T + t0) * DI;
  const short* xclr = xcl + ((size_t)b * T + t0) * DI;
  const float* bcr = xdbc + ((size_t)b * T + t0) * 64;
  float sd = 0.f;
  if (powA) {
    for (int t = 0; t < TC; t++) {
      const float* bc = bcr + (size_t)t * 64;
      float a = sb[tid];
#pragma unroll
      for (int j = 0; j < DTR; j++) a = fmaf(bc[j], sw[tid][j], a);
      float dt = (a > 20.f) ? a : __logf(1.f + __expf(a));
      float xv = join_bf16(xchr[(size_t)t * DI + d], xclr[(size_t)t * DI + d]);
      float dx = dt * xv;
      sd += dt;
      float ev[DSTATE];
      pow16(__expf(-dt), ev);
#pragma unroll
      for (int s = 0; s < DSTATE; s++) h[s] = h[s] * ev[s] + dx * bc[24 + s];
    }
  } else {
    for (int t = 0; t < TC; t++) {
      const float* bc = bcr + (size_t)t * 64;
      float a = sb[tid];
#pragma unroll
      for (int j = 0; j < DTR; j++) a = fmaf(bc[j], sw[tid][j], a);
      float dt = (a > 20.f) ? a : __logf(1.f + __expf(a));
      float xv = join_bf16(xchr[(size_t)t * DI + d], xclr[(size_t)t * DI + d]);
      float dx = dt * xv;
      sd += dt;
#pragma unroll
      for (int s = 0; s < DSTATE; s++)
        h[s] = h[s] * __expf(dt * A[s]) + dx * bc[24 + s];
    }
  }
  size_t o = ((size_t)(b * NCHUNK + ch) * DSTATE) * DI + d;
#pragma unroll
  for (int s = 0; s < DSTATE; s++) hchk[o + (size_t)s * DI] = h[s];
  sdt[(size_t)(b * NCHUNK + ch) * DI + d] = sd;
}

// Phase 2: per (b,s,d), NCHUNK-chunk recurrence; P recomputed from sdt.
__global__ __launch_bounds__(256) void scan_p2_k(float* __restrict__ hchk,
                                                 const float* __restrict__ sdt,
                                                 const float* __restrict__ alog) {
  int idx = blockIdx.x * 256 + threadIdx.x;  // [0, HB*DSTATE*DI)
  int d = idx % DI;
  int rem = idx / DI;
  int s = rem % DSTATE, b = rem / DSTATE;
  float A = -expf(alog[d * DSTATE + s]);
  float hin = 0.f;
#pragma unroll
  for (int ch = 0; ch < NCHUNK; ch++) {
    size_t o = ((size_t)(b * NCHUNK + ch) * DSTATE + s) * DI + d;
    float P = __expf(A * sdt[(size_t)(b * NCHUNK + ch) * DI + d]);
    float hl = hchk[o];
    hchk[o] = hin;
    hin = P * hin + hl;
  }
}

// Phase 3: rescan from incoming state; y = h.C + D*x, gated silu(z) -> planes.
__global__ __launch_bounds__(256) void scan_p3_k(
    const float* __restrict__ xzb, const short* __restrict__ xch,
    const short* __restrict__ xcl, const float* __restrict__ xdbc,
    const float* __restrict__ dtw, const float* __restrict__ dtb,
    const float* __restrict__ alog, const float* __restrict__ Dp,
    const float* __restrict__ hchk, short* __restrict__ yh,
    short* __restrict__ yl) {
  __shared__ float sw[256][25];
  __shared__ float sb[256];
  int tid = threadIdx.x;
  int d = blockIdx.x * 256 + tid;
  int ch = blockIdx.y, b = blockIdx.z;
  {
    const float* src = dtw + (size_t)blockIdx.x * 256 * DTR;
    for (int idx = tid; idx < 256 * DTR; idx += 256)
      sw[idx / DTR][idx % DTR] = src[idx];
    sb[tid] = dtb[d];
  }
  __syncthreads();
  float A[DSTATE], h[DSTATE];
  bool powA = true;
  size_t o = ((size_t)(b * NCHUNK + ch) * DSTATE) * DI + d;
#pragma unroll
  for (int s = 0; s < DSTATE; s++) {
    A[s] = -expf(alog[d * DSTATE + s]);
    powA = powA && (fabsf(A[s] + (float)(s + 1)) <= 1e-4f * (float)(s + 1));
    h[s] = hchk[o + (size_t)s * DI];
  }
  float Dd = Dp[d];
  const int t0 = ch * TC;
  const float* xzr = xzb + ((size_t)b * T + t0) * XZdim;
  const short* xchr = xch + ((size_t)b * T + t0) * DI;
  const short* xclr = xcl + ((size_t)b * T + t0) * DI;
  const float* bcr = xdbc + ((size_t)b * T + t0) * 64;
  if (powA) {
    for (int t = 0; t < TC; t++) {
      const float* bc = bcr + (size_t)t * 64;
      float a = sb[tid];
#pragma unroll
      for (int j = 0; j < DTR; j++) a = fmaf(bc[j], sw[tid][j], a);
      float dt = (a > 20.f) ? a : __logf(1.f + __expf(a));
      float xv = join_bf16(xchr[(size_t)t * DI + d], xclr[(size_t)t * DI + d]);
      float zv = xzr[(size_t)t * XZdim + DI + d];
      float dx = dt * xv;
      float accv = 0.f;
      float ev[DSTATE];
      pow16(__expf(-dt), ev);
#pragma unroll
      for (int s = 0; s < DSTATE; s++) {
        h[s] = h[s] * ev[s] + dx * bc[24 + s];
        accv += h[s] * bc[40 + s];
      }
      float y = accv + Dd * xv;
      float sz = zv / (1.f + __expf(-zv));
      float v = y * sz;
      short hh, ll;
      split_bf16(v, hh, ll);
      size_t oi = ((size_t)(b * T + t0 + t)) * DI + d;
      yh[oi] = hh;
      yl[oi] = ll;
    }
  } else {
    for (int t = 0; t < TC; t++) {
      const float* bc = bcr + (size_t)t * 64;
      float a = sb[tid];
#pragma unroll
      for (int j = 0; j < DTR; j++) a = fmaf(bc[j], sw[tid][j], a);
      float dt = (a > 20.f) ? a : __logf(1.f + __expf(a));
      float xv = join_bf16(xchr[(size_t)t * DI + d], xclr[(size_t)t * DI + d]);
      float zv = xzr[(size_t)t * XZdim + DI + d];
      float dx = dt * xv;
      float accv = 0.f;
#pragma unroll
      for (int s = 0; s < DSTATE; s++) {
        h[s] = h[s] * __expf(dt * A[s]) + dx * bc[24 + s];
        accv += h[s] * bc[40 + s];
      }
      float y = accv + Dd * xv;
      float sz = zv / (1.f + __expf(-zv));
      float v = y * sz;
      short hh, ll;
      split_bf16(v, hh, ll);
      size_t oi = ((size_t)(b * T + t0 + t)) * DI + d;
      yh[oi] = hh;
      yl[oi] = ll;
    }
  }
}

// ---------------- final LN + transpose scatter (contiguous writes) ---------
__global__ __launch_bounds__(256) void ln_scatter_k(
    const float* __restrict__ x, const float* __restrict__ stats,
    const float* __restrict__ g, const float* __restrict__ bb,
    float* __restrict__ out) {
  __shared__ float lds[64][129];
  int blk = blockIdx.x, tid = threadIdx.x;
  if (blk < 240) {
    int b = blk / 15, g_ = blk % 15;
    int sec = g_ / 5, s = g_ % 5;
    const int rbase = b * T + g_ * 64;
    for (int cc = 0; cc < 3; cc++) {
      if (cc) __syncthreads();
#pragma unroll
      for (int i = 0; i < 32; i++) {
        int lin = tid + 256 * i;  // [0, 8192)
        int p = lin >> 7, c = lin & 127;
        int row = rbase + p;
        int ccc = cc * 128 + c;
        float v = x[(size_t)row * C + ccc];
        v = (v - stats[2 * row]) * stats[2 * row + 1] * g[ccc] + bb[ccc];
        lds[p][c] = v;
      }
      __syncthreads();
      size_t obase = (size_t)sec * SEC_SZ +
                     (((size_t)(b * 5 + s) * C + cc * 128) << 6);
#pragma unroll
      for (int i = 0; i < 32; i++) {
        int lin = tid + 256 * i;
        int c = lin >> 6, p = lin & 63;
        out[obase + ((size_t)c << 6) + p] = lds[p][c];
      }
    }
  } else {
#pragma unroll
    for (int i = 0; i < 48; i++) {
      int lin = tid + 256 * i;
      int r = lin / C, c = lin % C;
      int b = r >> 1, e = r & 1;
      int row = b * T + NTOK + e;
      float v = x[(size_t)row * C + c];
      v = (v - stats[2 * row]) * stats[2 * row + 1] * g[c] + bb[c];
      out[3 * SEC_SZ + ((size_t)(b * 2 + e)) * C + c] = v;
    }
  }
}

// --------------------------------- launch ----------------------------------
extern "C" void kernel_launch(void* const* d_in, const int* in_sizes, int n_in,
                              void* d_out, int out_size, void* d_ws,
                              size_t ws_size, hipStream_t stream) {
  const float* image = (const float*)d_in[0];
  const float* lidar = (const float*)d_in[1];
  const float* radar = (const float*)d_in[2];
  const float* gps = (const float*)d_in[3];
  const float* pe = (const float*)d_in[4];
  const float* ln1g = (const float*)d_in[5];
  const float* ln1b = (const float*)d_in[6];
  const float* fc1w = (const float*)d_in[7];
  const float* fc1b = (const float*)d_in[8];
  const float* fc2w = (const float*)d_in[9];
  const float* fc2b_ = (const float*)d_in[10];
  const float* inw = (const float*)d_in[11];
  const float* cw = (const float*)d_in[12];
  const float* cb = (const float*)d_in[13];
  const float* xw = (const float*)d_in[14];
  const float* dtw = (const float*)d_in[15];
  const float* dtb = (const float*)d_in[16];
  const float* alog = (const float*)d_in[17];
  const float* Dp = (const float*)d_in[18];
  const float* ow = (const float*)d_in[19];
  const float* lnfg = (const float*)d_in[20];
  const float* lnfb = (const float*)d_in[21];
  float* out = (float*)d_out;

  // ------------- workspace carve-up (56.45M floats = 225.8 MB) -------------
  constexpr size_t MC = (size_t)M * C;  // 5,910,528
  float* ws = (float*)d_ws;
  float* x = ws;                            // MC (upper half aliases hchk)
  float* fcb = x + MC;                      // MC (fc2 lrelu result)
  float* bmfm = fcb + MC;                   // MC (ln planes alias; then bm)
  float* x1f = bmfm + MC;                   // MC (x1 planes)
  float* yf = x1f + MC;                     // MC (y planes, half-local)
  float* xz_h = yf + MC;                    // MH*1536
  float* xcp = xz_h + (size_t)MH * XZdim;   // MH*DI floats (xc planes)
  float* xdbc = xcp + (size_t)MH * DI;      // MH*64 fp32 [dt_r|B|C]
  float* wpl = xdbc + (size_t)MH * 64;      // weight planes

  // hchk/sdtb alias x upper half: x rows [MH,M) are dead from ln_fused
  // (layer start) until the dir0 combine writes, which happen after each
  // mamba call's scan_p3. CHK_H + sdt = 2,715,648 <= MC/2 = 2,955,264.
  constexpr size_t CHK_H = (size_t)HB * NCHUNK * DSTATE * DI;  // 2,555,904
  static_assert(CHK_H + (size_t)HB * NCHUNK * DI <= MC / 2, "alias overflow");
  float* hchk = x + MC / 2;
  float* sdtb = hchk + CHK_H;

  short* lnh = (short*)bmfm;  // ln planes dead before bm written
  short* lnl = lnh + MC;
  float* bm = bmfm;  // dir1 out_proj result (fp32, full M)
  short* x1h = (short*)x1f;
  short* x1l = x1h + MC;
  short* yh = (short*)yf;
  short* yl = yh + (size_t)MH * DI;
  short* xch = (short*)xcp;
  short* xcl = xch + (size_t)MH * DI;

  short* wf1h = (short*)wpl;
  short* wf1l = wf1h + WSZ1;
  short* wf2h = wf1l + WSZ1;
  short* wf2l = wf2h + WSZ1;
  short* winh = wf2l + WSZ1;
  short* winl = winh + WSZI;
  short* wowh = winl + WSZI;
  short* wowl = wowh + WSZO;
  short* wxh = wowl + WSZO;
  short* wxl = wxh + WSZX;
  float* stats2 = (float*)(wxl + WSZX);     // 2*M floats (final-LN stats)

  // ------------- weight casts to swizzled fragment order (per call) --------
  cast_swz_k<C, C, 12><<<dim3((int)(SET1 / 256), 4), 256, 0, stream>>>(
      fc1w, wf1h, wf1l);
  cast_swz_k<C, C, 12><<<dim3((int)(SET1 / 256), 4), 256, 0, stream>>>(
      fc2w, wf2h, wf2l);
  cast_swz_k<2 * DI, C, 12><<<dim3((int)(SETI / 256), 8), 256, 0, stream>>>(
      inw, winh, winl);
  cast_swz_k<C, DI, 24><<<dim3((int)(SETO / 256), 8), 256, 0, stream>>>(
      ow, wowh, wowl);
  cast_swz_k<ND, DI, 24><<<dim3((int)(SETX / 256), 8), 256, 0, stream>>>(
      xw, wxh, wxl);

  assemble_t_k<<<721, 256, 0, stream>>>(image, lidar, radar, gps, pe, x);

  for (int l = 0; l < NLAYER; l++) {
    ln_fused_k<<<M / 4, 256, 0, stream>>>(x, ln1g + l * C, ln1b + l * C, lnh,
                                          lnl);
    // fc1 = LN(x) @ fc1_w^T + b -> bf16 planes (XCD-chunked: nt=3, mpx=16)
    mgemm_k<0, true, false, true, false, true><<<384, 256, 0, stream>>>(
        lnh, lnl, C, wf1h + l * SET1, wf1l + l * SET1, C, fc1b + l * C,
        nullptr, 0, x1h, x1l, M, 0, 0, 3, 16);
    // fcb = lrelu(flip(xfc1) @ fc2_w^T + b) -> fp32 (XCD-chunked)
    mgemm_k<1, true, true, false, false, true><<<384, 256, 0, stream>>>(
        x1h, x1l, C, wf2h + l * SET1, wf2l + l * SET1, C, fc2b_ + l * C, fcb,
        C, nullptr, nullptr, M, 0, 0, 3, 16);
    // dir1 (backward) first -> bm; dir0 last fuses combine into x.
    for (int di = 0; di < 2; di++) {
      const int dir = 1 - di;
      size_t wo = (size_t)(l * 2 + dir);
      for (int h = 0; h < 2; h++) {
        const int roff = h * MH;
        // in_proj -> xz_h (XCD-chunked: nt=12, mpx=8, grid 768)
        if (dir == 0)
          mgemm_k<0, false, false, false, false, true><<<768, 256, 0, stream>>>(
              x1h, x1l, C, winh + wo * SETI, winl + wo * SETI, 2 * DI, nullptr,
              xz_h, XZdim, nullptr, nullptr, MH, roff, 0, 12, 8);
        else
          mgemm_k<0, false, true, false, false, true><<<768, 256, 0, stream>>>(
              x1h, x1l, C, winh + wo * SETI, winl + wo * SETI, 2 * DI, nullptr,
              xz_h, XZdim, nullptr, nullptr, MH, roff, 0, 12, 8);
        // causal depthwise conv + silu -> xc planes (8-t quad)
        conv_k<<<(HB * NQ8 * (DI / 2)) / 256, 256, 0, stream>>>(
            xz_h, cw + wo * DI * DCONV, cb + wo * DI, xch, xcl);
        // x_proj -> fp32 [dt_r|B|C] rows (stride 64); MT=16 tiles
        mgemm64_k<0, false, 16><<<dim3(1, MH / 16), 256, 0, stream>>>(
            xch, xcl, DI, DI, wxh + wo * SETX, wxl + wo * SETX, ND, nullptr,
            xdbc, 64, nullptr, nullptr, MH, 0, 0, 0);
        // chunked selective scan (dt inline) -> y planes
        scan_p1_k<<<dim3(3, NCHUNK, HB), 256, 0, stream>>>(
            xch, xcl, xdbc, dtw + wo * DI * DTR, dtb + wo * DI,
            alog + wo * DI * DSTATE, hchk, sdtb);
        scan_p2_k<<<(HB * DSTATE * DI) / 256, 256, 0, stream>>>(
            hchk, sdtb, alog + wo * DI * DSTATE);
        scan_p3_k<<<dim3(3, NCHUNK, HB), 256, 0, stream>>>(
            xz_h, xch, xcl, xdbc, dtw + wo * DI * DTR, dtb + wo * DI,
            alog + wo * DI * DSTATE, Dp + wo * DI, hchk, yh, yl);
        // out_proj (64^2, XCD-chunked: nt=6, mpx=16, grid 768)
        if (dir == 1)
          mgemm64_k<0, false, 64, true><<<768, 256, 0, stream>>>(
              yh, yl, DI, DI, wowh + wo * SETO, wowl + wo * SETO, C, nullptr,
              bm, C, nullptr, nullptr, MH, roff, 6, 16);
        else
          mgemm64_k<4, false, 64, true><<<768, 256, 0, stream>>>(
              yh, yl, DI, DI, wowh + wo * SETO, wowl + wo * SETO, C, nullptr,
              x, C, fcb, bm, MH, roff, 6, 16);
      }
    }
  }
  ln_stats2_k<<<M / 4, 256, 0, stream>>>(x, stats2);
  ln_scatter_k<<<241, 256, 0, stream>>>(x, stats2, lnfg, lnfb, out);
}

// Round 7
// 2911.766 us; speedup vs baseline: 1.0205x; 1.0205x over previous
//
#include <hip/hip_runtime.h>
#include <cstdint>
#include <cstddef>

// ---------------------------------------------------------------------------
// MambaFusion. R15 (on R14):
// R14 post-mortem: dt-fusion regressed scans (+6us each) because dtw was
// staged in LDS -> 24 ds_read_b32 per (t,thread) (~140cyc/wave/t); VALUBusy
// 28->50%, bank conflicts appeared. Traffic savings were real (FETCH 40->34MB).
// R15: dtw row -> 24 REGISTERS per thread (6x float4, 96B row is 16B-aligned,
// constant over t). Inner dot = 24 reg-fma. No LDS, no barrier. Keeps the
// dt_proj deletion + traffic win, removes the LDS-throughput bottleneck.
// Workspace: 56.45M floats = 225.8 MB (unchanged).
// ---------------------------------------------------------------------------

constexpr int BZv = 16, SEQ = 5, NV = 1;
constexpr int C = 384, DSTATE = 16, DCONV = 4, NLAYER = 4;
constexpr int DI = 768;
constexpr int DTR = 24;
constexpr int NTOK = (NV + 2) * SEQ * 64;  // 960
constexpr int T = NTOK + 2;                // 962
constexpr int M = BZv * T;                 // 15392
constexpr int HB = 8;                      // batches per half
constexpr int MH = HB * T;                 // 7696 rows per half
constexpr int XZdim = 2 * DI;              // 1536
constexpr int ND = DTR + 2 * DSTATE;       // 56
constexpr int NCHUNK = 26, TC = 37;        // 26*37 == 962
constexpr int NQ8 = 121;                   // ceil(T/8) 8-t quads
constexpr size_t SEC_SZ = (size_t)BZv * SEQ * C * 64;

// swizzled weight set sizes (elements per (layer[,dir]) set)
constexpr size_t SET1 = (size_t)C * C;        // 147,456 (fc)
constexpr size_t SETI = (size_t)2 * DI * C;   // 589,824 (in_proj)
constexpr size_t SETO = (size_t)C * DI;       // 294,912 (out_proj)
constexpr size_t SETX = (size_t)64 * DI;      // 49,152  (x_proj, N pad 56->64)
constexpr size_t WSZ1 = 4 * SET1;             // 589,824
constexpr size_t WSZI = 8 * SETI;             // 4,718,592
constexpr size_t WSZO = 8 * SETO;             // 2,359,296
constexpr size_t WSZX = 8 * SETX;             // 393,216

typedef __attribute__((ext_vector_type(8))) short short8;
typedef __attribute__((ext_vector_type(4))) float floatx4;

#define GLOAD_LDS16(g, l)                                        \
  __builtin_amdgcn_global_load_lds(                              \
      (const __attribute__((address_space(1))) void*)(g),        \
      (__attribute__((address_space(3))) void*)(l), 16, 0, 0)

__device__ __forceinline__ void split_bf16(float v, short& hi, short& lo) {
  unsigned u = __float_as_uint(v);
  unsigned hib = u & 0xFFFF0000u;      // truncate to bf16
  float r = v - __uint_as_float(hib);  // exact residual
  hi = (short)(hib >> 16);
  lo = (short)(__float_as_uint(r) >> 16);
}

__device__ __forceinline__ float join_bf16(short h, short l) {
  return __uint_as_float((unsigned)(unsigned short)h << 16) +
         __uint_as_float((unsigned)(unsigned short)l << 16);
}

// e[s] = e1^(s+1), 15 muls, ~4 deep.
__device__ __forceinline__ void pow16(float e1, float* e) {
  e[0] = e1;
  e[1] = e1 * e1;
  e[3] = e[1] * e[1];
  e[7] = e[3] * e[3];
  e[15] = e[7] * e[7];
  e[2] = e[1] * e[0];
  e[4] = e[3] * e[0];
  e[5] = e[3] * e[1];
  e[6] = e[5] * e[0];
  e[8] = e[7] * e[0];
  e[9] = e[7] * e[1];
  e[10] = e[9] * e[0];
  e[11] = e[7] * e[3];
  e[12] = e[11] * e[0];
  e[13] = e[11] * e[1];
  e[14] = e[13] * e[0];
}

// ------------------------------ token assembly -----------------------------
__global__ __launch_bounds__(256) void assemble_t_k(
    const float* __restrict__ img, const float* __restrict__ lid,
    const float* __restrict__ rad, const float* __restrict__ gps,
    const float* __restrict__ pe, float* __restrict__ x) {
  __shared__ float lds[64][129];
  int blk = blockIdx.x, tid = threadIdx.x;
  if (blk < 720) {
    int b = blk / 45;
    int rem = blk % 45;
    int g_ = rem / 3, cc = rem % 3;
    int sec = g_ / 5, s = g_ % 5;
    int srow = b * 5 + s;
    int which = (cc + sec) % 3;
    const float* src = (which == 0) ? img : (which == 1 ? lid : rad);
    const float* sp = src + (size_t)srow * (C * 64) + cc * 8192;
#pragma unroll
    for (int i = 0; i < 32; i++) {
      int lin = tid + 256 * i;
      lds[lin & 63][lin >> 6] = sp[lin];
    }
    __syncthreads();
#pragma unroll
    for (int i = 0; i < 32; i++) {
      int lin = tid + 256 * i;
      int p = lin >> 7, c = lin & 127;
      int t = g_ * 64 + p;
      int ccc = cc * 128 + c;
      x[((size_t)b * T + t) * C + ccc] = lds[p][c] + pe[(size_t)t * C + ccc];
    }
  } else {
#pragma unroll
    for (int i = 0; i < 48; i++) {
      int lin = tid + 256 * i;
      int r = lin / C, c = lin % C;
      int b = r >> 1, e = r & 1;
      x[((size_t)b * T + NTOK + e) * C + c] =
          gps[((size_t)b * 2 + e) * C + c] + pe[(size_t)(NTOK + e) * C + c];
    }
  }
}

// -------------------- fused LN (stats + apply -> planes) -------------------
__global__ __launch_bounds__(256) void ln_fused_k(
    const float* __restrict__ x, const float* __restrict__ g,
    const float* __restrict__ b, short* __restrict__ oh,
    short* __restrict__ ol) {
  int row = blockIdx.x * 4 + (threadIdx.x >> 6);
  int lane = threadIdx.x & 63;
  const float* xr = x + (size_t)row * C;
  float v[6];
  float s = 0.f;
#pragma unroll
  for (int j = 0; j < 6; j++) {
    v[j] = xr[lane + 64 * j];
    s += v[j];
  }
#pragma unroll
  for (int o = 32; o > 0; o >>= 1) s += __shfl_xor(s, o, 64);
  float mean = s * (1.f / 384.f);
  float q = 0.f;
#pragma unroll
  for (int j = 0; j < 6; j++) {
    float d = v[j] - mean;
    q += d * d;
  }
#pragma unroll
  for (int o = 32; o > 0; o >>= 1) q += __shfl_xor(q, o, 64);
  float rstd = rsqrtf(q * (1.f / 384.f) + 1e-5f);
#pragma unroll
  for (int j = 0; j < 6; j++) {
    int c = lane + 64 * j;
    float val = (v[j] - mean) * rstd * g[c] + b[c];
    short h, l;
    split_bf16(val, h, l);
    oh[(size_t)row * C + c] = h;
    ol[(size_t)row * C + c] = l;
  }
}

// ------------------------- LN row stats (final LN) -------------------------
__global__ __launch_bounds__(256) void ln_stats2_k(const float* __restrict__ x,
                                                   float* __restrict__ stats) {
  int row = blockIdx.x * 4 + (threadIdx.x >> 6);
  int lane = threadIdx.x & 63;
  const float* xr = x + (size_t)row * C;
  float v[6];
  float s = 0.f;
#pragma unroll
  for (int j = 0; j < 6; j++) {
    v[j] = xr[lane + 64 * j];
    s += v[j];
  }
#pragma unroll
  for (int o = 32; o > 0; o >>= 1) s += __shfl_xor(s, o, 64);
  float mean = s * (1.f / 384.f);
  float q = 0.f;
#pragma unroll
  for (int j = 0; j < 6; j++) {
    float d = v[j] - mean;
    q += d * d;
  }
#pragma unroll
  for (int o = 32; o > 0; o >>= 1) q += __shfl_xor(q, o, 64);
  if (lane == 0) {
    stats[2 * row] = mean;
    stats[2 * row + 1] = rsqrtf(q * (1.f / 384.f) + 1e-5f);
  }
}

// ------------------ weight cast to swizzled fragment order -----------------
// Output layout per set: idx = ((nf*KS + ks)*64 + lane)*8 + e, holding
// W[n = nf*16 + (lane&15)][k = ks*32 + (lane>>4)*8 + e], zero-padded when
// n >= NSRC or k >= KSRC. grid: (NP*KS*32/256, nsets).
template <int NSRC, int KSRC, int KS>
__global__ __launch_bounds__(256) void cast_swz_k(const float* __restrict__ src,
                                                  short* __restrict__ oh,
                                                  short* __restrict__ ol) {
  constexpr int NP = (NSRC + 15) & ~15;
  constexpr size_t SETSZ = (size_t)NP * KS * 32;
  int set = blockIdx.y;
  size_t idx = (size_t)blockIdx.x * 256 + threadIdx.x;
  int e = (int)(idx & 7);
  int lane = (int)((idx >> 3) & 63);
  size_t rest = idx >> 9;
  int ks = (int)(rest % KS);
  int nf = (int)(rest / KS);
  int n = nf * 16 + (lane & 15);
  int k = ks * 32 + ((lane >> 4) << 3) + e;
  float v = 0.f;
  if (n < NSRC && k < KSRC)
    v = src[(size_t)set * NSRC * KSRC + (size_t)n * KSRC + k];
  short h, l;
  split_bf16(v, h, l);
  oh[(size_t)set * SETSZ + idx] = h;
  ol[(size_t)set * SETSZ + idx] = l;
}

// ------------------ split-bf16 MFMA GEMM (128x128, B-direct) ---------------
// ACT: 0 none, 1 lrelu(0.2).
// OSPLIT: write hi/lo planes (stride N). W in swizzled fragment order.
// SWAPXY: m-tiles on blockIdx.x. XSWZ: flat 1-D grid, XCD-chunked decode
// (xcd = f%8 owns m-tiles [xcd*mpx, (xcd+1)*mpx), n fastest within).
template <int ACT, bool BIAS, bool FLIPA, bool OSPLIT, bool SWAPXY, bool XSWZ>
__global__ __launch_bounds__(256) void mgemm_k(
    const short* __restrict__ Ah, const short* __restrict__ Al, int K,
    const short* __restrict__ Wh, const short* __restrict__ Wl, int N,
    const float* __restrict__ bias, float* __restrict__ Co, int ldc,
    short* __restrict__ Oh, short* __restrict__ Ol, int Mrows, int arow_off,
    int crow_off, int nt, int mpx) {
  __shared__ __align__(16) short sAh[128 * 32];
  __shared__ __align__(16) short sAl[128 * 32];
  const int tid = threadIdx.x;
  const int wave = tid >> 6, lane = tid & 63;
  int bm_, bn_;
  if constexpr (XSWZ) {
    const int f = blockIdx.x;
    const int xcd = f & 7, j = f >> 3;
    bn_ = j % nt;
    bm_ = xcd * mpx + j / nt;
  } else {
    bm_ = SWAPXY ? blockIdx.x : blockIdx.y;
    bn_ = SWAPXY ? blockIdx.y : blockIdx.x;
  }
  const int m0 = bm_ * 128, n0 = bn_ * 128;
  const int lrow = lane >> 2, lchunk = lane & 3;
  const int wm = (wave >> 1) * 64, wn = (wave & 1) * 64;
  const int frow = lane & 15, fquad = lane >> 4;
  const int KST = K >> 5;
  const int nfb = (n0 + wn) >> 4;

  size_t arow[2];
#pragma unroll
  for (int p = 0; p < 2; p++) {
    int r = p * 64 + wave * 16 + lrow;
    int lm = m0 + r;
    if (lm >= Mrows) lm = Mrows - 1;
    int g = arow_off + lm;
    if (FLIPA) {
      int bb = g / T;
      int tt = g - bb * T;
      g = bb * T + (T - 1 - tt);
    }
    arow[p] = (size_t)g * K;
  }

  floatx4 acc[4][4] = {};
  for (int k0 = 0; k0 < K; k0 += 32) {
    if (k0) __syncthreads();
    const int kc = k0 + lchunk * 8;
#pragma unroll
    for (int p = 0; p < 2; p++) {
      GLOAD_LDS16(Ah + arow[p] + kc, &sAh[(p * 64 + wave * 16) * 32]);
      GLOAD_LDS16(Al + arow[p] + kc, &sAl[(p * 64 + wave * 16) * 32]);
    }
    const int ks = k0 >> 5;
    short8 bh[4], bl[4];
#pragma unroll
    for (int j = 0; j < 4; j++) {
      size_t bo = (((size_t)(nfb + j) * KST + ks) * 64 + lane) * 8;
      bh[j] = *(const short8*)&Wh[bo];
      bl[j] = *(const short8*)&Wl[bo];
    }
    __syncthreads();
    short8 ah[4], al[4];
#pragma unroll
    for (int i = 0; i < 4; i++) {
      int ra = (wm + i * 16 + frow) * 32 + fquad * 8;
      ah[i] = *(const short8*)&sAh[ra];
      al[i] = *(const short8*)&sAl[ra];
    }
#pragma unroll
    for (int i = 0; i < 4; i++)
#pragma unroll
      for (int j = 0; j < 4; j++) {
        acc[i][j] = __builtin_amdgcn_mfma_f32_16x16x32_bf16(ah[i], bh[j],
                                                            acc[i][j], 0, 0, 0);
        acc[i][j] = __builtin_amdgcn_mfma_f32_16x16x32_bf16(al[i], bh[j],
                                                            acc[i][j], 0, 0, 0);
        acc[i][j] = __builtin_amdgcn_mfma_f32_16x16x32_bf16(ah[i], bl[j],
                                                            acc[i][j], 0, 0, 0);
      }
  }
#pragma unroll
  for (int i = 0; i < 4; i++) {
#pragma unroll
    for (int r = 0; r < 4; r++) {
      int gm = m0 + wm + i * 16 + fquad * 4 + r;
      if (gm >= Mrows) continue;
      int grow = crow_off + gm;
#pragma unroll
      for (int j = 0; j < 4; j++) {
        int gn = n0 + wn + j * 16 + frow;
        if (gn >= N) continue;
        float v = acc[i][j][r];
        if constexpr (BIAS) v += bias[gn];
        if constexpr (ACT == 1) v = v >= 0.f ? v : 0.2f * v;
        if constexpr (OSPLIT) {
          short h, l;
          split_bf16(v, h, l);
          Oh[(size_t)grow * N + gn] = h;
          Ol[(size_t)grow * N + gn] = l;
        } else {
          Co[(size_t)grow * ldc + gn] = v;
        }
      }
    }
  }
}

// ------------------- split-bf16 MFMA GEMM (MTx64, B-direct) ----------------
// fp32 Co output, stride ldc, cols gn < N.
// ACT: 0 none, 4 combine v = e2*(e1 + v) (stride ldc).
// MT: m-tile rows. XSWZ: flat grid, XCD-chunked decode (see mgemm_k).
template <int ACT, bool BIAS, int MT = 64, bool XSWZ = false>
__global__ __launch_bounds__(256) void mgemm64_k(
    const short* __restrict__ Ah, const short* __restrict__ Al, int lda, int K,
    const short* __restrict__ Wh, const short* __restrict__ Wl, int N,
    const float* __restrict__ bias, float* __restrict__ Co, int ldc,
    const float* __restrict__ e1, const float* __restrict__ e2, int Mrows,
    int crow_off, int nt, int mpx) {
  __shared__ __align__(16) short sAh[MT * 32];
  __shared__ __align__(16) short sAl[MT * 32];
  const int tid = threadIdx.x;
  const int wave = tid >> 6, lane = tid & 63;
  int bm_, bn_;
  if constexpr (XSWZ) {
    const int f = blockIdx.x;
    const int xcd = f & 7, j = f >> 3;
    bn_ = j % nt;
    bm_ = xcd * mpx + j / nt;
  } else {
    bm_ = blockIdx.y;
    bn_ = blockIdx.x;
  }
  const int m0 = bm_ * MT, n0 = bn_ * 64;
  const int schunk = tid & 3;
  const int frow = lane & 15, fquad = lane >> 4;
  const int KST = K >> 5;
  const int nfw = (n0 >> 4) + wave;

  int lm = m0 + ((MT == 64) ? (tid >> 2) : (lane >> 2));
  if (lm >= Mrows) lm = Mrows - 1;
  size_t aoff = (size_t)lm * lda;

  floatx4 acc[MT / 16] = {};
  for (int k0 = 0; k0 < K; k0 += 32) {
    if (k0) __syncthreads();
    const int kc = k0 + schunk * 8;
    if constexpr (MT == 64) {
      GLOAD_LDS16(Ah + aoff + kc, &sAh[(wave * 16) * 32]);
      GLOAD_LDS16(Al + aoff + kc, &sAl[(wave * 16) * 32]);
    } else {
      if (wave == 0) GLOAD_LDS16(Ah + aoff + kc, &sAh[0]);
      if (wave == 1) GLOAD_LDS16(Al + aoff + kc, &sAl[0]);
    }
    const int ks = k0 >> 5;
    short8 bh, bl;
    {
      size_t bo = (((size_t)nfw * KST + ks) * 64 + lane) * 8;
      bh = *(const short8*)&Wh[bo];
      bl = *(const short8*)&Wl[bo];
    }
    __syncthreads();
    short8 ah[MT / 16], al[MT / 16];
#pragma unroll
    for (int i = 0; i < MT / 16; i++) {
      int ra = (i * 16 + frow) * 32 + fquad * 8;
      ah[i] = *(const short8*)&sAh[ra];
      al[i] = *(const short8*)&sAl[ra];
    }
#pragma unroll
    for (int i = 0; i < MT / 16; i++) {
      acc[i] = __builtin_amdgcn_mfma_f32_16x16x32_bf16(ah[i], bh, acc[i], 0, 0, 0);
      acc[i] = __builtin_amdgcn_mfma_f32_16x16x32_bf16(al[i], bh, acc[i], 0, 0, 0);
      acc[i] = __builtin_amdgcn_mfma_f32_16x16x32_bf16(ah[i], bl, acc[i], 0, 0, 0);
    }
  }
  const int gn = n0 + wave * 16 + frow;
  if (gn < N) {
#pragma unroll
    for (int i = 0; i < MT / 16; i++) {
#pragma unroll
      for (int r = 0; r < 4; r++) {
        int gm = m0 + i * 16 + fquad * 4 + r;
        if (gm >= Mrows) continue;
        int grow = crow_off + gm;
        float v = acc[i][r];
        if constexpr (BIAS) v += bias[gn];
        if constexpr (ACT == 4) {
          size_t o = (size_t)grow * ldc + gn;
          v = e2[o] * (e1[o] + v);
        }
        Co[(size_t)grow * ldc + gn] = v;
      }
    }
  }
}

// --------------------------- depthwise conv + silu -------------------------
// 8-t sliding-window: thread per (b, 8t-quad, d-pair); 11 row-loads ->
// 8 outputs from registers (amp 1.375). Emits xc bf16 hi/lo planes.
__global__ __launch_bounds__(256) void conv_k(const float* __restrict__ xz,
                                              const float* __restrict__ cw,
                                              const float* __restrict__ cb,
                                              short* __restrict__ xch,
                                              short* __restrict__ xcl) {
  int idx = blockIdx.x * 256 + threadIdx.x;  // [0, HB*NQ8*384)
  int dh = idx % (DI / 2);
  int rem = idx / (DI / 2);
  int q = rem % NQ8;
  int b = rem / NQ8;
  int d = dh * 2;
  int t0 = q * 8;
  const float* base = xz + (size_t)b * T * XZdim + d;
  float4 cwa = *(const float4*)&cw[d * 4];
  float4 cwb = *(const float4*)&cw[(d + 1) * 4];
  float cb0 = cb[d], cb1 = cb[d + 1];
  float2 w[11];
#pragma unroll
  for (int j = 0; j < 11; j++) {
    int tt = t0 - 3 + j;
    w[j] = (tt >= 0 && tt < T) ? *(const float2*)(base + (size_t)tt * XZdim)
                               : make_float2(0.f, 0.f);
  }
  const float cwx[4] = {cwa.x, cwa.y, cwa.z, cwa.w};
  const float cwy[4] = {cwb.x, cwb.y, cwb.z, cwb.w};
#pragma unroll
  for (int r = 0; r < 8; r++) {
    int t = t0 + r;
    if (t >= T) break;
    float a0 = cb0, a1 = cb1;
#pragma unroll
    for (int j = 0; j < 4; j++) {
      a0 += w[r + j].x * cwx[j];
      a1 += w[r + j].y * cwy[j];
    }
    float v0 = a0 / (1.f + __expf(-a0));
    float v1 = a1 / (1.f + __expf(-a1));
    short h0, l0, h1, l1;
    split_bf16(v0, h0, l0);
    split_bf16(v1, h1, l1);
    size_t o = ((size_t)b * T + t) * DI + d;
    *(short2*)&xch[o] = make_short2(h0, h1);
    *(short2*)&xcl[o] = make_short2(l0, l1);
  }
}

// ----------------------- chunked selective scan ----------------------------
// dt computed inline: dt = softplus(dt_r . dtw_d + dtb_d); dtw row held in
// 24 REGISTERS per thread (constant over t); dt_r from the fp32 xdbc row
// (block-uniform broadcast). xdbc row layout (stride 64): [dt_r|B|C].

// Phase 1: local scan from h=0; stores h_local[16] + sum(dt) per (b,ch,d).
__global__ __launch_bounds__(256) void scan_p1_k(
    const short* __restrict__ xch, const short* __restrict__ xcl,
    const float* __restrict__ xdbc, const float* __restrict__ dtw,
    const float* __restrict__ dtb, const float* __restrict__ alog,
    float* __restrict__ hchk, float* __restrict__ sdt) {
  int tid = threadIdx.x;
  int d = blockIdx.x * 256 + tid;
  int ch = blockIdx.y, b = blockIdx.z;
  float wreg[DTR];
  {
    const float* wd = dtw + (size_t)d * DTR;
#pragma unroll
    for (int j = 0; j < DTR; j += 4) {
      float4 t4 = *(const float4*)(wd + j);
      wreg[j] = t4.x;
      wreg[j + 1] = t4.y;
      wreg[j + 2] = t4.z;
      wreg[j + 3] = t4.w;
    }
  }
  const float dbias = dtb[d];
  float A[DSTATE], h[DSTATE];
  bool powA = true;
#pragma unroll
  for (int s = 0; s < DSTATE; s++) {
    A[s] = -expf(alog[d * DSTATE + s]);
    powA = powA && (fabsf(A[s] + (float)(s + 1)) <= 1e-4f * (float)(s + 1));
    h[s] = 0.f;
  }
  const int t0 = ch * TC;
  const short* xchr = xch + ((size_t)b * T + t0) * DI;
  const short* xclr = xcl + ((size_t)b * T + t0) * DI;
  const float* bcr = xdbc + ((size_t)b * T + t0) * 64;
  float sd = 0.f;
  if (powA) {
    for (int t = 0; t < TC; t++) {
      const float* bc = bcr + (size_t)t * 64;
      float a = dbias;
#pragma unroll
      for (int j = 0; j < DTR; j++) a = fmaf(bc[j], wreg[j], a);
      float dt = (a > 20.f) ? a : __logf(1.f + __expf(a));
      float xv = join_bf16(xchr[(size_t)t * DI + d], xclr[(size_t)t * DI + d]);
      float dx = dt * xv;
      sd += dt;
      float ev[DSTATE];
      pow16(__expf(-dt), ev);
#pragma unroll
      for (int s = 0; s < DSTATE; s++) h[s] = h[s] * ev[s] + dx * bc[24 + s];
    }
  } else {
    for (int t = 0; t < TC; t++) {
      const float* bc = bcr + (size_t)t * 64;
      float a = dbias;
#pragma unroll
      for (int j = 0; j < DTR; j++) a = fmaf(bc[j], wreg[j], a);
      float dt = (a > 20.f) ? a : __logf(1.f + __expf(a));
      float xv = join_bf16(xchr[(size_t)t * DI + d], xclr[(size_t)t * DI + d]);
      float dx = dt * xv;
      sd += dt;
#pragma unroll
      for (int s = 0; s < DSTATE; s++)
        h[s] = h[s] * __expf(dt * A[s]) + dx * bc[24 + s];
    }
  }
  size_t o = ((size_t)(b * NCHUNK + ch) * DSTATE) * DI + d;
#pragma unroll
  for (int s = 0; s < DSTATE; s++) hchk[o + (size_t)s * DI] = h[s];
  sdt[(size_t)(b * NCHUNK + ch) * DI + d] = sd;
}

// Phase 2: per (b,s,d), NCHUNK-chunk recurrence; P recomputed from sdt.
__global__ __launch_bounds__(256) void scan_p2_k(float* __restrict__ hchk,
                                                 const float* __restrict__ sdt,
                                                 const float* __restrict__ alog) {
  int idx = blockIdx.x * 256 + threadIdx.x;  // [0, HB*DSTATE*DI)
  int d = idx % DI;
  int rem = idx / DI;
  int s = rem % DSTATE, b = rem / DSTATE;
  float A = -expf(alog[d * DSTATE + s]);
  float hin = 0.f;
#pragma unroll
  for (int ch = 0; ch < NCHUNK; ch++) {
    size_t o = ((size_t)(b * NCHUNK + ch) * DSTATE + s) * DI + d;
    float P = __expf(A * sdt[(size_t)(b * NCHUNK + ch) * DI + d]);
    float hl = hchk[o];
    hchk[o] = hin;
    hin = P * hin + hl;
  }
}

// Phase 3: rescan from incoming state; y = h.C + D*x, gated silu(z) -> planes.
__global__ __launch_bounds__(256) void scan_p3_k(
    const float* __restrict__ xzb, const short* __restrict__ xch,
    const short* __restrict__ xcl, const float* __restrict__ xdbc,
    const float* __restrict__ dtw, const float* __restrict__ dtb,
    const float* __restrict__ alog, const float* __restrict__ Dp,
    const float* __restrict__ hchk, short* __restrict__ yh,
    short* __restrict__ yl) {
  int tid = threadIdx.x;
  int d = blockIdx.x * 256 + tid;
  int ch = blockIdx.y, b = blockIdx.z;
  float wreg[DTR];
  {
    const float* wd = dtw + (size_t)d * DTR;
#pragma unroll
    for (int j = 0; j < DTR; j += 4) {
      float4 t4 = *(const float4*)(wd + j);
      wreg[j] = t4.x;
      wreg[j + 1] = t4.y;
      wreg[j + 2] = t4.z;
      wreg[j + 3] = t4.w;
    }
  }
  const float dbias = dtb[d];
  float A[DSTATE], h[DSTATE];
  bool powA = true;
  size_t o = ((size_t)(b * NCHUNK + ch) * DSTATE) * DI + d;
#pragma unroll
  for (int s = 0; s < DSTATE; s++) {
    A[s] = -expf(alog[d * DSTATE + s]);
    powA = powA && (fabsf(A[s] + (float)(s + 1)) <= 1e-4f * (float)(s + 1));
    h[s] = hchk[o + (size_t)s * DI];
  }
  float Dd = Dp[d];
  const int t0 = ch * TC;
  const float* xzr = xzb + ((size_t)b * T + t0) * XZdim;
  const short* xchr = xch + ((size_t)b * T + t0) * DI;
  const short* xclr = xcl + ((size_t)b * T + t0) * DI;
  const float* bcr = xdbc + ((size_t)b * T + t0) * 64;
  if (powA) {
    for (int t = 0; t < TC; t++) {
      const float* bc = bcr + (size_t)t * 64;
      float a = dbias;
#pragma unroll
      for (int j = 0; j < DTR; j++) a = fmaf(bc[j], wreg[j], a);
      float dt = (a > 20.f) ? a : __logf(1.f + __expf(a));
      float xv = join_bf16(xchr[(size_t)t * DI + d], xclr[(size_t)t * DI + d]);
      float zv = xzr[(size_t)t * XZdim + DI + d];
      float dx = dt * xv;
      float accv = 0.f;
      float ev[DSTATE];
      pow16(__expf(-dt), ev);
#pragma unroll
      for (int s = 0; s < DSTATE; s++) {
        h[s] = h[s] * ev[s] + dx * bc[24 + s];
        accv += h[s] * bc[40 + s];
      }
      float y = accv + Dd * xv;
      float sz = zv / (1.f + __expf(-zv));
      float v = y * sz;
      short hh, ll;
      split_bf16(v, hh, ll);
      size_t oi = ((size_t)(b * T + t0 + t)) * DI + d;
      yh[oi] = hh;
      yl[oi] = ll;
    }
  } else {
    for (int t = 0; t < TC; t++) {
      const float* bc = bcr + (size_t)t * 64;
      float a = dbias;
#pragma unroll
      for (int j = 0; j < DTR; j++) a = fmaf(bc[j], wreg[j], a);
      float dt = (a > 20.f) ? a : __logf(1.f + __expf(a));
      float xv = join_bf16(xchr[(size_t)t * DI + d], xclr[(size_t)t * DI + d]);
      float zv = xzr[(size_t)t * XZdim + DI + d];
      float dx = dt * xv;
      float accv = 0.f;
#pragma unroll
      for (int s = 0; s < DSTATE; s++) {
        h[s] = h[s] * __expf(dt * A[s]) + dx * bc[24 + s];
        accv += h[s] * bc[40 + s];
      }
      float y = accv + Dd * xv;
      float sz = zv / (1.f + __expf(-zv));
      float v = y * sz;
      short hh, ll;
      split_bf16(v, hh, ll);
      size_t oi = ((size_t)(b * T + t0 + t)) * DI + d;
      yh[oi] = hh;
      yl[oi] = ll;
    }
  }
}

// ---------------- final LN + transpose scatter (contiguous writes) ---------
__global__ __launch_bounds__(256) void ln_scatter_k(
    const float* __restrict__ x, const float* __restrict__ stats,
    const float* __restrict__ g, const float* __restrict__ bb,
    float* __restrict__ out) {
  __shared__ float lds[64][129];
  int blk = blockIdx.x, tid = threadIdx.x;
  if (blk < 240) {
    int b = blk / 15, g_ = blk % 15;
    int sec = g_ / 5, s = g_ % 5;
    const int rbase = b * T + g_ * 64;
    for (int cc = 0; cc < 3; cc++) {
      if (cc) __syncthreads();
#pragma unroll
      for (int i = 0; i < 32; i++) {
        int lin = tid + 256 * i;  // [0, 8192)
        int p = lin >> 7, c = lin & 127;
        int row = rbase + p;
        int ccc = cc * 128 + c;
        float v = x[(size_t)row * C + ccc];
        v = (v - stats[2 * row]) * stats[2 * row + 1] * g[ccc] + bb[ccc];
        lds[p][c] = v;
      }
      __syncthreads();
      size_t obase = (size_t)sec * SEC_SZ +
                     (((size_t)(b * 5 + s) * C + cc * 128) << 6);
#pragma unroll
      for (int i = 0; i < 32; i++) {
        int lin = tid + 256 * i;
        int c = lin >> 6, p = lin & 63;
        out[obase + ((size_t)c << 6) + p] = lds[p][c];
      }
    }
  } else {
#pragma unroll
    for (int i = 0; i < 48; i++) {
      int lin = tid + 256 * i;
      int r = lin / C, c = lin % C;
      int b = r >> 1, e = r & 1;
      int row = b * T + NTOK + e;
      float v = x[(size_t)row * C + c];
      v = (v - stats[2 * row]) * stats[2 * row + 1] * g[c] + bb[c];
      out[3 * SEC_SZ + ((size_t)(b * 2 + e)) * C + c] = v;
    }
  }
}

// --------------------------------- launch ----------------------------------
extern "C" void kernel_launch(void* const* d_in, const int* in_sizes, int n_in,
                              void* d_out, int out_size, void* d_ws,
                              size_t ws_size, hipStream_t stream) {
  const float* image = (const float*)d_in[0];
  const float* lidar = (const float*)d_in[1];
  const float* radar = (const float*)d_in[2];
  const float* gps = (const float*)d_in[3];
  const float* pe = (const float*)d_in[4];
  const float* ln1g = (const float*)d_in[5];
  const float* ln1b = (const float*)d_in[6];
  const float* fc1w = (const float*)d_in[7];
  const float* fc1b = (const float*)d_in[8];
  const float* fc2w = (const float*)d_in[9];
  const float* fc2b_ = (const float*)d_in[10];
  const float* inw = (const float*)d_in[11];
  const float* cw = (const float*)d_in[12];
  const float* cb = (const float*)d_in[13];
  const float* xw = (const float*)d_in[14];
  const float* dtw = (const float*)d_in[15];
  const float* dtb = (const float*)d_in[16];
  const float* alog = (const float*)d_in[17];
  const float* Dp = (const float*)d_in[18];
  const float* ow = (const float*)d_in[19];
  const float* lnfg = (const float*)d_in[20];
  const float* lnfb = (const float*)d_in[21];
  float* out = (float*)d_out;

  // ------------- workspace carve-up (56.45M floats = 225.8 MB) -------------
  constexpr size_t MC = (size_t)M * C;  // 5,910,528
  float* ws = (float*)d_ws;
  float* x = ws;                            // MC (upper half aliases hchk)
  float* fcb = x + MC;                      // MC (fc2 lrelu result)
  float* bmfm = fcb + MC;                   // MC (ln planes alias; then bm)
  float* x1f = bmfm + MC;                   // MC (x1 planes)
  float* yf = x1f + MC;                     // MC (y planes, half-local)
  float* xz_h = yf + MC;                    // MH*1536
  float* xcp = xz_h + (size_t)MH * XZdim;   // MH*DI floats (xc planes)
  float* xdbc = xcp + (size_t)MH * DI;      // MH*64 fp32 [dt_r|B|C]
  float* wpl = xdbc + (size_t)MH * 64;      // weight planes

  // hchk/sdtb alias x upper half: x rows [MH,M) are dead from ln_fused
  // (layer start) until the dir0 combine writes, which happen after each
  // mamba call's scan_p3. CHK_H + sdt = 2,715,648 <= MC/2 = 2,955,264.
  constexpr size_t CHK_H = (size_t)HB * NCHUNK * DSTATE * DI;  // 2,555,904
  static_assert(CHK_H + (size_t)HB * NCHUNK * DI <= MC / 2, "alias overflow");
  float* hchk = x + MC / 2;
  float* sdtb = hchk + CHK_H;

  short* lnh = (short*)bmfm;  // ln planes dead before bm written
  short* lnl = lnh + MC;
  float* bm = bmfm;  // dir1 out_proj result (fp32, full M)
  short* x1h = (short*)x1f;
  short* x1l = x1h + MC;
  short* yh = (short*)yf;
  short* yl = yh + (size_t)MH * DI;
  short* xch = (short*)xcp;
  short* xcl = xch + (size_t)MH * DI;

  short* wf1h = (short*)wpl;
  short* wf1l = wf1h + WSZ1;
  short* wf2h = wf1l + WSZ1;
  short* wf2l = wf2h + WSZ1;
  short* winh = wf2l + WSZ1;
  short* winl = winh + WSZI;
  short* wowh = winl + WSZI;
  short* wowl = wowh + WSZO;
  short* wxh = wowl + WSZO;
  short* wxl = wxh + WSZX;
  float* stats2 = (float*)(wxl + WSZX);     // 2*M floats (final-LN stats)

  // ------------- weight casts to swizzled fragment order (per call) --------
  cast_swz_k<C, C, 12><<<dim3((int)(SET1 / 256), 4), 256, 0, stream>>>(
      fc1w, wf1h, wf1l);
  cast_swz_k<C, C, 12><<<dim3((int)(SET1 / 256), 4), 256, 0, stream>>>(
      fc2w, wf2h, wf2l);
  cast_swz_k<2 * DI, C, 12><<<dim3((int)(SETI / 256), 8), 256, 0, stream>>>(
      inw, winh, winl);
  cast_swz_k<C, DI, 24><<<dim3((int)(SETO / 256), 8), 256, 0, stream>>>(
      ow, wowh, wowl);
  cast_swz_k<ND, DI, 24><<<dim3((int)(SETX / 256), 8), 256, 0, stream>>>(
      xw, wxh, wxl);

  assemble_t_k<<<721, 256, 0, stream>>>(image, lidar, radar, gps, pe, x);

  for (int l = 0; l < NLAYER; l++) {
    ln_fused_k<<<M / 4, 256, 0, stream>>>(x, ln1g + l * C, ln1b + l * C, lnh,
                                          lnl);
    // fc1 = LN(x) @ fc1_w^T + b -> bf16 planes (XCD-chunked: nt=3, mpx=16)
    mgemm_k<0, true, false, true, false, true><<<384, 256, 0, stream>>>(
        lnh, lnl, C, wf1h + l * SET1, wf1l + l * SET1, C, fc1b + l * C,
        nullptr, 0, x1h, x1l, M, 0, 0, 3, 16);
    // fcb = lrelu(flip(xfc1) @ fc2_w^T + b) -> fp32 (XCD-chunked)
    mgemm_k<1, true, true, false, false, true><<<384, 256, 0, stream>>>(
        x1h, x1l, C, wf2h + l * SET1, wf2l + l * SET1, C, fc2b_ + l * C, fcb,
        C, nullptr, nullptr, M, 0, 0, 3, 16);
    // dir1 (backward) first -> bm; dir0 last fuses combine into x.
    for (int di = 0; di < 2; di++) {
      const int dir = 1 - di;
      size_t wo = (size_t)(l * 2 + dir);
      for (int h = 0; h < 2; h++) {
        const int roff = h * MH;
        // in_proj -> xz_h (XCD-chunked: nt=12, mpx=8, grid 768)
        if (dir == 0)
          mgemm_k<0, false, false, false, false, true><<<768, 256, 0, stream>>>(
              x1h, x1l, C, winh + wo * SETI, winl + wo * SETI, 2 * DI, nullptr,
              xz_h, XZdim, nullptr, nullptr, MH, roff, 0, 12, 8);
        else
          mgemm_k<0, false, true, false, false, true><<<768, 256, 0, stream>>>(
              x1h, x1l, C, winh + wo * SETI, winl + wo * SETI, 2 * DI, nullptr,
              xz_h, XZdim, nullptr, nullptr, MH, roff, 0, 12, 8);
        // causal depthwise conv + silu -> xc planes (8-t quad)
        conv_k<<<(HB * NQ8 * (DI / 2)) / 256, 256, 0, stream>>>(
            xz_h, cw + wo * DI * DCONV, cb + wo * DI, xch, xcl);
        // x_proj -> fp32 [dt_r|B|C] rows (stride 64); MT=16 tiles
        mgemm64_k<0, false, 16><<<dim3(1, MH / 16), 256, 0, stream>>>(
            xch, xcl, DI, DI, wxh + wo * SETX, wxl + wo * SETX, ND, nullptr,
            xdbc, 64, nullptr, nullptr, MH, 0, 0, 0);
        // chunked selective scan (dt inline, reg-resident dtw) -> y planes
        scan_p1_k<<<dim3(3, NCHUNK, HB), 256, 0, stream>>>(
            xch, xcl, xdbc, dtw + wo * DI * DTR, dtb + wo * DI,
            alog + wo * DI * DSTATE, hchk, sdtb);
        scan_p2_k<<<(HB * DSTATE * DI) / 256, 256, 0, stream>>>(
            hchk, sdtb, alog + wo * DI * DSTATE);
        scan_p3_k<<<dim3(3, NCHUNK, HB), 256, 0, stream>>>(
            xz_h, xch, xcl, xdbc, dtw + wo * DI * DTR, dtb + wo * DI,
            alog + wo * DI * DSTATE, Dp + wo * DI, hchk, yh, yl);
        // out_proj (64^2, XCD-chunked: nt=6, mpx=16, grid 768)
        if (dir == 1)
          mgemm64_k<0, false, 64, true><<<768, 256, 0, stream>>>(
              yh, yl, DI, DI, wowh + wo * SETO, wowl + wo * SETO, C, nullptr,
              bm, C, nullptr, nullptr, MH, roff, 6, 16);
        else
          mgemm64_k<4, false, 64, true><<<768, 256, 0, stream>>>(
              yh, yl, DI, DI, wowh + wo * SETO, wowl + wo * SETO, C, nullptr,
              x, C, fcb, bm, MH, roff, 6, 16);
      }
    }
  }
  ln_stats2_k<<<M / 4, 256, 0, stream>>>(x, stats2);
  ln_scatter_k<<<241, 256, 0, stream>>>(x, stats2, lnfg, lnfb, out);
}

// Round 8
// 2888.595 us; speedup vs baseline: 1.0287x; 1.0080x over previous
//
#include <hip/hip_runtime.h>
#include <cstdint>
#include <cstddef>

// ---------------------------------------------------------------------------
// MambaFusion. R16 (on R15):
// R15 post-mortem: reg-resident dtw removed LDS conflicts (119808->0) but
// scan_p3 still 42us @ Occ 17%, VALU 47%, HBM 17% = latency-bound at 2.4
// blocks/CU with 37-step chains; the inline-dt VALU sits on the critical
// path. R16: NCHUNK 26->37 (TC=26; 962=2*13*37): 888 blocks = 3.5/CU,
// chains -30%. hchk too big for the x-alias -> dedicated region; workspace
// 241.3MB (fits: harness fillBuffer re-poisons 256MiB, so ws >= 256MiB).
// ---------------------------------------------------------------------------

constexpr int BZv = 16, SEQ = 5, NV = 1;
constexpr int C = 384, DSTATE = 16, DCONV = 4, NLAYER = 4;
constexpr int DI = 768;
constexpr int DTR = 24;
constexpr int NTOK = (NV + 2) * SEQ * 64;  // 960
constexpr int T = NTOK + 2;                // 962
constexpr int M = BZv * T;                 // 15392
constexpr int HB = 8;                      // batches per half
constexpr int MH = HB * T;                 // 7696 rows per half
constexpr int XZdim = 2 * DI;              // 1536
constexpr int ND = DTR + 2 * DSTATE;       // 56
constexpr int NCHUNK = 37, TC = 26;        // 37*26 == 962
constexpr int NQ8 = 121;                   // ceil(T/8) 8-t quads
constexpr size_t SEC_SZ = (size_t)BZv * SEQ * C * 64;

// swizzled weight set sizes (elements per (layer[,dir]) set)
constexpr size_t SET1 = (size_t)C * C;        // 147,456 (fc)
constexpr size_t SETI = (size_t)2 * DI * C;   // 589,824 (in_proj)
constexpr size_t SETO = (size_t)C * DI;       // 294,912 (out_proj)
constexpr size_t SETX = (size_t)64 * DI;      // 49,152  (x_proj, N pad 56->64)
constexpr size_t WSZ1 = 4 * SET1;             // 589,824
constexpr size_t WSZI = 8 * SETI;             // 4,718,592
constexpr size_t WSZO = 8 * SETO;             // 2,359,296
constexpr size_t WSZX = 8 * SETX;             // 393,216

typedef __attribute__((ext_vector_type(8))) short short8;
typedef __attribute__((ext_vector_type(4))) float floatx4;

#define GLOAD_LDS16(g, l)                                        \
  __builtin_amdgcn_global_load_lds(                              \
      (const __attribute__((address_space(1))) void*)(g),        \
      (__attribute__((address_space(3))) void*)(l), 16, 0, 0)

__device__ __forceinline__ void split_bf16(float v, short& hi, short& lo) {
  unsigned u = __float_as_uint(v);
  unsigned hib = u & 0xFFFF0000u;      // truncate to bf16
  float r = v - __uint_as_float(hib);  // exact residual
  hi = (short)(hib >> 16);
  lo = (short)(__float_as_uint(r) >> 16);
}

__device__ __forceinline__ float join_bf16(short h, short l) {
  return __uint_as_float((unsigned)(unsigned short)h << 16) +
         __uint_as_float((unsigned)(unsigned short)l << 16);
}

// e[s] = e1^(s+1), 15 muls, ~4 deep.
__device__ __forceinline__ void pow16(float e1, float* e) {
  e[0] = e1;
  e[1] = e1 * e1;
  e[3] = e[1] * e[1];
  e[7] = e[3] * e[3];
  e[15] = e[7] * e[7];
  e[2] = e[1] * e[0];
  e[4] = e[3] * e[0];
  e[5] = e[3] * e[1];
  e[6] = e[5] * e[0];
  e[8] = e[7] * e[0];
  e[9] = e[7] * e[1];
  e[10] = e[9] * e[0];
  e[11] = e[7] * e[3];
  e[12] = e[11] * e[0];
  e[13] = e[11] * e[1];
  e[14] = e[13] * e[0];
}

// ------------------------------ token assembly -----------------------------
__global__ __launch_bounds__(256) void assemble_t_k(
    const float* __restrict__ img, const float* __restrict__ lid,
    const float* __restrict__ rad, const float* __restrict__ gps,
    const float* __restrict__ pe, float* __restrict__ x) {
  __shared__ float lds[64][129];
  int blk = blockIdx.x, tid = threadIdx.x;
  if (blk < 720) {
    int b = blk / 45;
    int rem = blk % 45;
    int g_ = rem / 3, cc = rem % 3;
    int sec = g_ / 5, s = g_ % 5;
    int srow = b * 5 + s;
    int which = (cc + sec) % 3;
    const float* src = (which == 0) ? img : (which == 1 ? lid : rad);
    const float* sp = src + (size_t)srow * (C * 64) + cc * 8192;
#pragma unroll
    for (int i = 0; i < 32; i++) {
      int lin = tid + 256 * i;
      lds[lin & 63][lin >> 6] = sp[lin];
    }
    __syncthreads();
#pragma unroll
    for (int i = 0; i < 32; i++) {
      int lin = tid + 256 * i;
      int p = lin >> 7, c = lin & 127;
      int t = g_ * 64 + p;
      int ccc = cc * 128 + c;
      x[((size_t)b * T + t) * C + ccc] = lds[p][c] + pe[(size_t)t * C + ccc];
    }
  } else {
#pragma unroll
    for (int i = 0; i < 48; i++) {
      int lin = tid + 256 * i;
      int r = lin / C, c = lin % C;
      int b = r >> 1, e = r & 1;
      x[((size_t)b * T + NTOK + e) * C + c] =
          gps[((size_t)b * 2 + e) * C + c] + pe[(size_t)(NTOK + e) * C + c];
    }
  }
}

// -------------------- fused LN (stats + apply -> planes) -------------------
__global__ __launch_bounds__(256) void ln_fused_k(
    const float* __restrict__ x, const float* __restrict__ g,
    const float* __restrict__ b, short* __restrict__ oh,
    short* __restrict__ ol) {
  int row = blockIdx.x * 4 + (threadIdx.x >> 6);
  int lane = threadIdx.x & 63;
  const float* xr = x + (size_t)row * C;
  float v[6];
  float s = 0.f;
#pragma unroll
  for (int j = 0; j < 6; j++) {
    v[j] = xr[lane + 64 * j];
    s += v[j];
  }
#pragma unroll
  for (int o = 32; o > 0; o >>= 1) s += __shfl_xor(s, o, 64);
  float mean = s * (1.f / 384.f);
  float q = 0.f;
#pragma unroll
  for (int j = 0; j < 6; j++) {
    float d = v[j] - mean;
    q += d * d;
  }
#pragma unroll
  for (int o = 32; o > 0; o >>= 1) q += __shfl_xor(q, o, 64);
  float rstd = rsqrtf(q * (1.f / 384.f) + 1e-5f);
#pragma unroll
  for (int j = 0; j < 6; j++) {
    int c = lane + 64 * j;
    float val = (v[j] - mean) * rstd * g[c] + b[c];
    short h, l;
    split_bf16(val, h, l);
    oh[(size_t)row * C + c] = h;
    ol[(size_t)row * C + c] = l;
  }
}

// ------------------------- LN row stats (final LN) -------------------------
__global__ __launch_bounds__(256) void ln_stats2_k(const float* __restrict__ x,
                                                   float* __restrict__ stats) {
  int row = blockIdx.x * 4 + (threadIdx.x >> 6);
  int lane = threadIdx.x & 63;
  const float* xr = x + (size_t)row * C;
  float v[6];
  float s = 0.f;
#pragma unroll
  for (int j = 0; j < 6; j++) {
    v[j] = xr[lane + 64 * j];
    s += v[j];
  }
#pragma unroll
  for (int o = 32; o > 0; o >>= 1) s += __shfl_xor(s, o, 64);
  float mean = s * (1.f / 384.f);
  float q = 0.f;
#pragma unroll
  for (int j = 0; j < 6; j++) {
    float d = v[j] - mean;
    q += d * d;
  }
#pragma unroll
  for (int o = 32; o > 0; o >>= 1) q += __shfl_xor(q, o, 64);
  if (lane == 0) {
    stats[2 * row] = mean;
    stats[2 * row + 1] = rsqrtf(q * (1.f / 384.f) + 1e-5f);
  }
}

// ------------------ weight cast to swizzled fragment order -----------------
// Output layout per set: idx = ((nf*KS + ks)*64 + lane)*8 + e, holding
// W[n = nf*16 + (lane&15)][k = ks*32 + (lane>>4)*8 + e], zero-padded when
// n >= NSRC or k >= KSRC. grid: (NP*KS*32/256, nsets).
template <int NSRC, int KSRC, int KS>
__global__ __launch_bounds__(256) void cast_swz_k(const float* __restrict__ src,
                                                  short* __restrict__ oh,
                                                  short* __restrict__ ol) {
  constexpr int NP = (NSRC + 15) & ~15;
  constexpr size_t SETSZ = (size_t)NP * KS * 32;
  int set = blockIdx.y;
  size_t idx = (size_t)blockIdx.x * 256 + threadIdx.x;
  int e = (int)(idx & 7);
  int lane = (int)((idx >> 3) & 63);
  size_t rest = idx >> 9;
  int ks = (int)(rest % KS);
  int nf = (int)(rest / KS);
  int n = nf * 16 + (lane & 15);
  int k = ks * 32 + ((lane >> 4) << 3) + e;
  float v = 0.f;
  if (n < NSRC && k < KSRC)
    v = src[(size_t)set * NSRC * KSRC + (size_t)n * KSRC + k];
  short h, l;
  split_bf16(v, h, l);
  oh[(size_t)set * SETSZ + idx] = h;
  ol[(size_t)set * SETSZ + idx] = l;
}

// ------------------ split-bf16 MFMA GEMM (128x128, B-direct) ---------------
// ACT: 0 none, 1 lrelu(0.2).
// OSPLIT: write hi/lo planes (stride N). W in swizzled fragment order.
// SWAPXY: m-tiles on blockIdx.x. XSWZ: flat 1-D grid, XCD-chunked decode
// (xcd = f%8 owns m-tiles [xcd*mpx, (xcd+1)*mpx), n fastest within).
template <int ACT, bool BIAS, bool FLIPA, bool OSPLIT, bool SWAPXY, bool XSWZ>
__global__ __launch_bounds__(256) void mgemm_k(
    const short* __restrict__ Ah, const short* __restrict__ Al, int K,
    const short* __restrict__ Wh, const short* __restrict__ Wl, int N,
    const float* __restrict__ bias, float* __restrict__ Co, int ldc,
    short* __restrict__ Oh, short* __restrict__ Ol, int Mrows, int arow_off,
    int crow_off, int nt, int mpx) {
  __shared__ __align__(16) short sAh[128 * 32];
  __shared__ __align__(16) short sAl[128 * 32];
  const int tid = threadIdx.x;
  const int wave = tid >> 6, lane = tid & 63;
  int bm_, bn_;
  if constexpr (XSWZ) {
    const int f = blockIdx.x;
    const int xcd = f & 7, j = f >> 3;
    bn_ = j % nt;
    bm_ = xcd * mpx + j / nt;
  } else {
    bm_ = SWAPXY ? blockIdx.x : blockIdx.y;
    bn_ = SWAPXY ? blockIdx.y : blockIdx.x;
  }
  const int m0 = bm_ * 128, n0 = bn_ * 128;
  const int lrow = lane >> 2, lchunk = lane & 3;
  const int wm = (wave >> 1) * 64, wn = (wave & 1) * 64;
  const int frow = lane & 15, fquad = lane >> 4;
  const int KST = K >> 5;
  const int nfb = (n0 + wn) >> 4;

  size_t arow[2];
#pragma unroll
  for (int p = 0; p < 2; p++) {
    int r = p * 64 + wave * 16 + lrow;
    int lm = m0 + r;
    if (lm >= Mrows) lm = Mrows - 1;
    int g = arow_off + lm;
    if (FLIPA) {
      int bb = g / T;
      int tt = g - bb * T;
      g = bb * T + (T - 1 - tt);
    }
    arow[p] = (size_t)g * K;
  }

  floatx4 acc[4][4] = {};
  for (int k0 = 0; k0 < K; k0 += 32) {
    if (k0) __syncthreads();
    const int kc = k0 + lchunk * 8;
#pragma unroll
    for (int p = 0; p < 2; p++) {
      GLOAD_LDS16(Ah + arow[p] + kc, &sAh[(p * 64 + wave * 16) * 32]);
      GLOAD_LDS16(Al + arow[p] + kc, &sAl[(p * 64 + wave * 16) * 32]);
    }
    const int ks = k0 >> 5;
    short8 bh[4], bl[4];
#pragma unroll
    for (int j = 0; j < 4; j++) {
      size_t bo = (((size_t)(nfb + j) * KST + ks) * 64 + lane) * 8;
      bh[j] = *(const short8*)&Wh[bo];
      bl[j] = *(const short8*)&Wl[bo];
    }
    __syncthreads();
    short8 ah[4], al[4];
#pragma unroll
    for (int i = 0; i < 4; i++) {
      int ra = (wm + i * 16 + frow) * 32 + fquad * 8;
      ah[i] = *(const short8*)&sAh[ra];
      al[i] = *(const short8*)&sAl[ra];
    }
#pragma unroll
    for (int i = 0; i < 4; i++)
#pragma unroll
      for (int j = 0; j < 4; j++) {
        acc[i][j] = __builtin_amdgcn_mfma_f32_16x16x32_bf16(ah[i], bh[j],
                                                            acc[i][j], 0, 0, 0);
        acc[i][j] = __builtin_amdgcn_mfma_f32_16x16x32_bf16(al[i], bh[j],
                                                            acc[i][j], 0, 0, 0);
        acc[i][j] = __builtin_amdgcn_mfma_f32_16x16x32_bf16(ah[i], bl[j],
                                                            acc[i][j], 0, 0, 0);
      }
  }
#pragma unroll
  for (int i = 0; i < 4; i++) {
#pragma unroll
    for (int r = 0; r < 4; r++) {
      int gm = m0 + wm + i * 16 + fquad * 4 + r;
      if (gm >= Mrows) continue;
      int grow = crow_off + gm;
#pragma unroll
      for (int j = 0; j < 4; j++) {
        int gn = n0 + wn + j * 16 + frow;
        if (gn >= N) continue;
        float v = acc[i][j][r];
        if constexpr (BIAS) v += bias[gn];
        if constexpr (ACT == 1) v = v >= 0.f ? v : 0.2f * v;
        if constexpr (OSPLIT) {
          short h, l;
          split_bf16(v, h, l);
          Oh[(size_t)grow * N + gn] = h;
          Ol[(size_t)grow * N + gn] = l;
        } else {
          Co[(size_t)grow * ldc + gn] = v;
        }
      }
    }
  }
}

// ------------------- split-bf16 MFMA GEMM (MTx64, B-direct) ----------------
// fp32 Co output, stride ldc, cols gn < N.
// ACT: 0 none, 4 combine v = e2*(e1 + v) (stride ldc).
// MT: m-tile rows. XSWZ: flat grid, XCD-chunked decode (see mgemm_k).
template <int ACT, bool BIAS, int MT = 64, bool XSWZ = false>
__global__ __launch_bounds__(256) void mgemm64_k(
    const short* __restrict__ Ah, const short* __restrict__ Al, int lda, int K,
    const short* __restrict__ Wh, const short* __restrict__ Wl, int N,
    const float* __restrict__ bias, float* __restrict__ Co, int ldc,
    const float* __restrict__ e1, const float* __restrict__ e2, int Mrows,
    int crow_off, int nt, int mpx) {
  __shared__ __align__(16) short sAh[MT * 32];
  __shared__ __align__(16) short sAl[MT * 32];
  const int tid = threadIdx.x;
  const int wave = tid >> 6, lane = tid & 63;
  int bm_, bn_;
  if constexpr (XSWZ) {
    const int f = blockIdx.x;
    const int xcd = f & 7, j = f >> 3;
    bn_ = j % nt;
    bm_ = xcd * mpx + j / nt;
  } else {
    bm_ = blockIdx.y;
    bn_ = blockIdx.x;
  }
  const int m0 = bm_ * MT, n0 = bn_ * 64;
  const int schunk = tid & 3;
  const int frow = lane & 15, fquad = lane >> 4;
  const int KST = K >> 5;
  const int nfw = (n0 >> 4) + wave;

  int lm = m0 + ((MT == 64) ? (tid >> 2) : (lane >> 2));
  if (lm >= Mrows) lm = Mrows - 1;
  size_t aoff = (size_t)lm * lda;

  floatx4 acc[MT / 16] = {};
  for (int k0 = 0; k0 < K; k0 += 32) {
    if (k0) __syncthreads();
    const int kc = k0 + schunk * 8;
    if constexpr (MT == 64) {
      GLOAD_LDS16(Ah + aoff + kc, &sAh[(wave * 16) * 32]);
      GLOAD_LDS16(Al + aoff + kc, &sAl[(wave * 16) * 32]);
    } else {
      if (wave == 0) GLOAD_LDS16(Ah + aoff + kc, &sAh[0]);
      if (wave == 1) GLOAD_LDS16(Al + aoff + kc, &sAl[0]);
    }
    const int ks = k0 >> 5;
    short8 bh, bl;
    {
      size_t bo = (((size_t)nfw * KST + ks) * 64 + lane) * 8;
      bh = *(const short8*)&Wh[bo];
      bl = *(const short8*)&Wl[bo];
    }
    __syncthreads();
    short8 ah[MT / 16], al[MT / 16];
#pragma unroll
    for (int i = 0; i < MT / 16; i++) {
      int ra = (i * 16 + frow) * 32 + fquad * 8;
      ah[i] = *(const short8*)&sAh[ra];
      al[i] = *(const short8*)&sAl[ra];
    }
#pragma unroll
    for (int i = 0; i < MT / 16; i++) {
      acc[i] = __builtin_amdgcn_mfma_f32_16x16x32_bf16(ah[i], bh, acc[i], 0, 0, 0);
      acc[i] = __builtin_amdgcn_mfma_f32_16x16x32_bf16(al[i], bh, acc[i], 0, 0, 0);
      acc[i] = __builtin_amdgcn_mfma_f32_16x16x32_bf16(ah[i], bl, acc[i], 0, 0, 0);
    }
  }
  const int gn = n0 + wave * 16 + frow;
  if (gn < N) {
#pragma unroll
    for (int i = 0; i < MT / 16; i++) {
#pragma unroll
      for (int r = 0; r < 4; r++) {
        int gm = m0 + i * 16 + fquad * 4 + r;
        if (gm >= Mrows) continue;
        int grow = crow_off + gm;
        float v = acc[i][r];
        if constexpr (BIAS) v += bias[gn];
        if constexpr (ACT == 4) {
          size_t o = (size_t)grow * ldc + gn;
          v = e2[o] * (e1[o] + v);
        }
        Co[(size_t)grow * ldc + gn] = v;
      }
    }
  }
}

// --------------------------- depthwise conv + silu -------------------------
// 8-t sliding-window: thread per (b, 8t-quad, d-pair); 11 row-loads ->
// 8 outputs from registers (amp 1.375). Emits xc bf16 hi/lo planes.
__global__ __launch_bounds__(256) void conv_k(const float* __restrict__ xz,
                                              const float* __restrict__ cw,
                                              const float* __restrict__ cb,
                                              short* __restrict__ xch,
                                              short* __restrict__ xcl) {
  int idx = blockIdx.x * 256 + threadIdx.x;  // [0, HB*NQ8*384)
  int dh = idx % (DI / 2);
  int rem = idx / (DI / 2);
  int q = rem % NQ8;
  int b = rem / NQ8;
  int d = dh * 2;
  int t0 = q * 8;
  const float* base = xz + (size_t)b * T * XZdim + d;
  float4 cwa = *(const float4*)&cw[d * 4];
  float4 cwb = *(const float4*)&cw[(d + 1) * 4];
  float cb0 = cb[d], cb1 = cb[d + 1];
  float2 w[11];
#pragma unroll
  for (int j = 0; j < 11; j++) {
    int tt = t0 - 3 + j;
    w[j] = (tt >= 0 && tt < T) ? *(const float2*)(base + (size_t)tt * XZdim)
                               : make_float2(0.f, 0.f);
  }
  const float cwx[4] = {cwa.x, cwa.y, cwa.z, cwa.w};
  const float cwy[4] = {cwb.x, cwb.y, cwb.z, cwb.w};
#pragma unroll
  for (int r = 0; r < 8; r++) {
    int t = t0 + r;
    if (t >= T) break;
    float a0 = cb0, a1 = cb1;
#pragma unroll
    for (int j = 0; j < 4; j++) {
      a0 += w[r + j].x * cwx[j];
      a1 += w[r + j].y * cwy[j];
    }
    float v0 = a0 / (1.f + __expf(-a0));
    float v1 = a1 / (1.f + __expf(-a1));
    short h0, l0, h1, l1;
    split_bf16(v0, h0, l0);
    split_bf16(v1, h1, l1);
    size_t o = ((size_t)b * T + t) * DI + d;
    *(short2*)&xch[o] = make_short2(h0, h1);
    *(short2*)&xcl[o] = make_short2(l0, l1);
  }
}

// ----------------------- chunked selective scan ----------------------------
// dt computed inline: dt = softplus(dt_r . dtw_d + dtb_d); dtw row held in
// 24 REGISTERS per thread (constant over t); dt_r from the fp32 xdbc row
// (block-uniform broadcast). xdbc row layout (stride 64): [dt_r|B|C].

// Phase 1: local scan from h=0; stores h_local[16] + sum(dt) per (b,ch,d).
__global__ __launch_bounds__(256) void scan_p1_k(
    const short* __restrict__ xch, const short* __restrict__ xcl,
    const float* __restrict__ xdbc, const float* __restrict__ dtw,
    const float* __restrict__ dtb, const float* __restrict__ alog,
    float* __restrict__ hchk, float* __restrict__ sdt) {
  int tid = threadIdx.x;
  int d = blockIdx.x * 256 + tid;
  int ch = blockIdx.y, b = blockIdx.z;
  float wreg[DTR];
  {
    const float* wd = dtw + (size_t)d * DTR;
#pragma unroll
    for (int j = 0; j < DTR; j += 4) {
      float4 t4 = *(const float4*)(wd + j);
      wreg[j] = t4.x;
      wreg[j + 1] = t4.y;
      wreg[j + 2] = t4.z;
      wreg[j + 3] = t4.w;
    }
  }
  const float dbias = dtb[d];
  float A[DSTATE], h[DSTATE];
  bool powA = true;
#pragma unroll
  for (int s = 0; s < DSTATE; s++) {
    A[s] = -expf(alog[d * DSTATE + s]);
    powA = powA && (fabsf(A[s] + (float)(s + 1)) <= 1e-4f * (float)(s + 1));
    h[s] = 0.f;
  }
  const int t0 = ch * TC;
  const short* xchr = xch + ((size_t)b * T + t0) * DI;
  const short* xclr = xcl + ((size_t)b * T + t0) * DI;
  const float* bcr = xdbc + ((size_t)b * T + t0) * 64;
  float sd = 0.f;
  if (powA) {
    for (int t = 0; t < TC; t++) {
      const float* bc = bcr + (size_t)t * 64;
      float a = dbias;
#pragma unroll
      for (int j = 0; j < DTR; j++) a = fmaf(bc[j], wreg[j], a);
      float dt = (a > 20.f) ? a : __logf(1.f + __expf(a));
      float xv = join_bf16(xchr[(size_t)t * DI + d], xclr[(size_t)t * DI + d]);
      float dx = dt * xv;
      sd += dt;
      float ev[DSTATE];
      pow16(__expf(-dt), ev);
#pragma unroll
      for (int s = 0; s < DSTATE; s++) h[s] = h[s] * ev[s] + dx * bc[24 + s];
    }
  } else {
    for (int t = 0; t < TC; t++) {
      const float* bc = bcr + (size_t)t * 64;
      float a = dbias;
#pragma unroll
      for (int j = 0; j < DTR; j++) a = fmaf(bc[j], wreg[j], a);
      float dt = (a > 20.f) ? a : __logf(1.f + __expf(a));
      float xv = join_bf16(xchr[(size_t)t * DI + d], xclr[(size_t)t * DI + d]);
      float dx = dt * xv;
      sd += dt;
#pragma unroll
      for (int s = 0; s < DSTATE; s++)
        h[s] = h[s] * __expf(dt * A[s]) + dx * bc[24 + s];
    }
  }
  size_t o = ((size_t)(b * NCHUNK + ch) * DSTATE) * DI + d;
#pragma unroll
  for (int s = 0; s < DSTATE; s++) hchk[o + (size_t)s * DI] = h[s];
  sdt[(size_t)(b * NCHUNK + ch) * DI + d] = sd;
}

// Phase 2: per (b,s,d), NCHUNK-chunk recurrence; P recomputed from sdt.
__global__ __launch_bounds__(256) void scan_p2_k(float* __restrict__ hchk,
                                                 const float* __restrict__ sdt,
                                                 const float* __restrict__ alog) {
  int idx = blockIdx.x * 256 + threadIdx.x;  // [0, HB*DSTATE*DI)
  int d = idx % DI;
  int rem = idx / DI;
  int s = rem % DSTATE, b = rem / DSTATE;
  float A = -expf(alog[d * DSTATE + s]);
  float hin = 0.f;
#pragma unroll
  for (int ch = 0; ch < NCHUNK; ch++) {
    size_t o = ((size_t)(b * NCHUNK + ch) * DSTATE + s) * DI + d;
    float P = __expf(A * sdt[(size_t)(b * NCHUNK + ch) * DI + d]);
    float hl = hchk[o];
    hchk[o] = hin;
    hin = P * hin + hl;
  }
}

// Phase 3: rescan from incoming state; y = h.C + D*x, gated silu(z) -> planes.
__global__ __launch_bounds__(256) void scan_p3_k(
    const float* __restrict__ xzb, const short* __restrict__ xch,
    const short* __restrict__ xcl, const float* __restrict__ xdbc,
    const float* __restrict__ dtw, const float* __restrict__ dtb,
    const float* __restrict__ alog, const float* __restrict__ Dp,
    const float* __restrict__ hchk, short* __restrict__ yh,
    short* __restrict__ yl) {
  int tid = threadIdx.x;
  int d = blockIdx.x * 256 + tid;
  int ch = blockIdx.y, b = blockIdx.z;
  float wreg[DTR];
  {
    const float* wd = dtw + (size_t)d * DTR;
#pragma unroll
    for (int j = 0; j < DTR; j += 4) {
      float4 t4 = *(const float4*)(wd + j);
      wreg[j] = t4.x;
      wreg[j + 1] = t4.y;
      wreg[j + 2] = t4.z;
      wreg[j + 3] = t4.w;
    }
  }
  const float dbias = dtb[d];
  float A[DSTATE], h[DSTATE];
  bool powA = true;
  size_t o = ((size_t)(b * NCHUNK + ch) * DSTATE) * DI + d;
#pragma unroll
  for (int s = 0; s < DSTATE; s++) {
    A[s] = -expf(alog[d * DSTATE + s]);
    powA = powA && (fabsf(A[s] + (float)(s + 1)) <= 1e-4f * (float)(s + 1));
    h[s] = hchk[o + (size_t)s * DI];
  }
  float Dd = Dp[d];
  const int t0 = ch * TC;
  const float* xzr = xzb + ((size_t)b * T + t0) * XZdim;
  const short* xchr = xch + ((size_t)b * T + t0) * DI;
  const short* xclr = xcl + ((size_t)b * T + t0) * DI;
  const float* bcr = xdbc + ((size_t)b * T + t0) * 64;
  if (powA) {
    for (int t = 0; t < TC; t++) {
      const float* bc = bcr + (size_t)t * 64;
      float a = dbias;
#pragma unroll
      for (int j = 0; j < DTR; j++) a = fmaf(bc[j], wreg[j], a);
      float dt = (a > 20.f) ? a : __logf(1.f + __expf(a));
      float xv = join_bf16(xchr[(size_t)t * DI + d], xclr[(size_t)t * DI + d]);
      float zv = xzr[(size_t)t * XZdim + DI + d];
      float dx = dt * xv;
      float accv = 0.f;
      float ev[DSTATE];
      pow16(__expf(-dt), ev);
#pragma unroll
      for (int s = 0; s < DSTATE; s++) {
        h[s] = h[s] * ev[s] + dx * bc[24 + s];
        accv += h[s] * bc[40 + s];
      }
      float y = accv + Dd * xv;
      float sz = zv / (1.f + __expf(-zv));
      float v = y * sz;
      short hh, ll;
      split_bf16(v, hh, ll);
      size_t oi = ((size_t)(b * T + t0 + t)) * DI + d;
      yh[oi] = hh;
      yl[oi] = ll;
    }
  } else {
    for (int t = 0; t < TC; t++) {
      const float* bc = bcr + (size_t)t * 64;
      float a = dbias;
#pragma unroll
      for (int j = 0; j < DTR; j++) a = fmaf(bc[j], wreg[j], a);
      float dt = (a > 20.f) ? a : __logf(1.f + __expf(a));
      float xv = join_bf16(xchr[(size_t)t * DI + d], xclr[(size_t)t * DI + d]);
      float zv = xzr[(size_t)t * XZdim + DI + d];
      float dx = dt * xv;
      float accv = 0.f;
#pragma unroll
      for (int s = 0; s < DSTATE; s++) {
        h[s] = h[s] * __expf(dt * A[s]) + dx * bc[24 + s];
        accv += h[s] * bc[40 + s];
      }
      float y = accv + Dd * xv;
      float sz = zv / (1.f + __expf(-zv));
      float v = y * sz;
      short hh, ll;
      split_bf16(v, hh, ll);
      size_t oi = ((size_t)(b * T + t0 + t)) * DI + d;
      yh[oi] = hh;
      yl[oi] = ll;
    }
  }
}

// ---------------- final LN + transpose scatter (contiguous writes) ---------
__global__ __launch_bounds__(256) void ln_scatter_k(
    const float* __restrict__ x, const float* __restrict__ stats,
    const float* __restrict__ g, const float* __restrict__ bb,
    float* __restrict__ out) {
  __shared__ float lds[64][129];
  int blk = blockIdx.x, tid = threadIdx.x;
  if (blk < 240) {
    int b = blk / 15, g_ = blk % 15;
    int sec = g_ / 5, s = g_ % 5;
    const int rbase = b * T + g_ * 64;
    for (int cc = 0; cc < 3; cc++) {
      if (cc) __syncthreads();
#pragma unroll
      for (int i = 0; i < 32; i++) {
        int lin = tid + 256 * i;  // [0, 8192)
        int p = lin >> 7, c = lin & 127;
        int row = rbase + p;
        int ccc = cc * 128 + c;
        float v = x[(size_t)row * C + ccc];
        v = (v - stats[2 * row]) * stats[2 * row + 1] * g[ccc] + bb[ccc];
        lds[p][c] = v;
      }
      __syncthreads();
      size_t obase = (size_t)sec * SEC_SZ +
                     (((size_t)(b * 5 + s) * C + cc * 128) << 6);
#pragma unroll
      for (int i = 0; i < 32; i++) {
        int lin = tid + 256 * i;
        int c = lin >> 6, p = lin & 63;
        out[obase + ((size_t)c << 6) + p] = lds[p][c];
      }
    }
  } else {
#pragma unroll
    for (int i = 0; i < 48; i++) {
      int lin = tid + 256 * i;
      int r = lin / C, c = lin % C;
      int b = r >> 1, e = r & 1;
      int row = b * T + NTOK + e;
      float v = x[(size_t)row * C + c];
      v = (v - stats[2 * row]) * stats[2 * row + 1] * g[c] + bb[c];
      out[3 * SEC_SZ + ((size_t)(b * 2 + e)) * C + c] = v;
    }
  }
}

// --------------------------------- launch ----------------------------------
extern "C" void kernel_launch(void* const* d_in, const int* in_sizes, int n_in,
                              void* d_out, int out_size, void* d_ws,
                              size_t ws_size, hipStream_t stream) {
  const float* image = (const float*)d_in[0];
  const float* lidar = (const float*)d_in[1];
  const float* radar = (const float*)d_in[2];
  const float* gps = (const float*)d_in[3];
  const float* pe = (const float*)d_in[4];
  const float* ln1g = (const float*)d_in[5];
  const float* ln1b = (const float*)d_in[6];
  const float* fc1w = (const float*)d_in[7];
  const float* fc1b = (const float*)d_in[8];
  const float* fc2w = (const float*)d_in[9];
  const float* fc2b_ = (const float*)d_in[10];
  const float* inw = (const float*)d_in[11];
  const float* cw = (const float*)d_in[12];
  const float* cb = (const float*)d_in[13];
  const float* xw = (const float*)d_in[14];
  const float* dtw = (const float*)d_in[15];
  const float* dtb = (const float*)d_in[16];
  const float* alog = (const float*)d_in[17];
  const float* Dp = (const float*)d_in[18];
  const float* ow = (const float*)d_in[19];
  const float* lnfg = (const float*)d_in[20];
  const float* lnfb = (const float*)d_in[21];
  float* out = (float*)d_out;

  // ------------- workspace carve-up (60.32M floats = 241.3 MB) -------------
  constexpr size_t MC = (size_t)M * C;  // 5,910,528
  float* ws = (float*)d_ws;
  float* x = ws;                            // MC
  float* fcb = x + MC;                      // MC (fc2 lrelu result)
  float* bmfm = fcb + MC;                   // MC (ln planes alias; then bm)
  float* x1f = bmfm + MC;                   // MC (x1 planes)
  float* yf = x1f + MC;                     // MC (y planes, half-local)
  float* xz_h = yf + MC;                    // MH*1536
  float* xcp = xz_h + (size_t)MH * XZdim;   // MH*DI floats (xc planes)
  float* xdbc = xcp + (size_t)MH * DI;      // MH*64 fp32 [dt_r|B|C]
  float* wpl = xdbc + (size_t)MH * 64;      // weight planes

  short* lnh = (short*)bmfm;  // ln planes dead before bm written
  short* lnl = lnh + MC;
  float* bm = bmfm;  // dir1 out_proj result (fp32, full M)
  short* x1h = (short*)x1f;
  short* x1l = x1h + MC;
  short* yh = (short*)yf;
  short* yl = yh + (size_t)MH * DI;
  short* xch = (short*)xcp;
  short* xcl = xch + (size_t)MH * DI;

  short* wf1h = (short*)wpl;
  short* wf1l = wf1h + WSZ1;
  short* wf2h = wf1l + WSZ1;
  short* wf2l = wf2h + WSZ1;
  short* winh = wf2l + WSZ1;
  short* winl = winh + WSZI;
  short* wowh = winl + WSZI;
  short* wowl = wowh + WSZO;
  short* wxh = wowl + WSZO;
  short* wxl = wxh + WSZX;
  float* stats2 = (float*)(wxl + WSZX);     // 2*M floats (final-LN stats)
  // dedicated scan-state region (NCHUNK=37 too big for the old x-alias)
  constexpr size_t CHK_H = (size_t)HB * NCHUNK * DSTATE * DI;  // 3,637,248
  float* hchk = stats2 + 2 * (size_t)M;
  float* sdtb = hchk + CHK_H;               // HB*NCHUNK*DI = 227,328

  // ------------- weight casts to swizzled fragment order (per call) --------
  cast_swz_k<C, C, 12><<<dim3((int)(SET1 / 256), 4), 256, 0, stream>>>(
      fc1w, wf1h, wf1l);
  cast_swz_k<C, C, 12><<<dim3((int)(SET1 / 256), 4), 256, 0, stream>>>(
      fc2w, wf2h, wf2l);
  cast_swz_k<2 * DI, C, 12><<<dim3((int)(SETI / 256), 8), 256, 0, stream>>>(
      inw, winh, winl);
  cast_swz_k<C, DI, 24><<<dim3((int)(SETO / 256), 8), 256, 0, stream>>>(
      ow, wowh, wowl);
  cast_swz_k<ND, DI, 24><<<dim3((int)(SETX / 256), 8), 256, 0, stream>>>(
      xw, wxh, wxl);

  assemble_t_k<<<721, 256, 0, stream>>>(image, lidar, radar, gps, pe, x);

  for (int l = 0; l < NLAYER; l++) {
    ln_fused_k<<<M / 4, 256, 0, stream>>>(x, ln1g + l * C, ln1b + l * C, lnh,
                                          lnl);
    // fc1 = LN(x) @ fc1_w^T + b -> bf16 planes (XCD-chunked: nt=3, mpx=16)
    mgemm_k<0, true, false, true, false, true><<<384, 256, 0, stream>>>(
        lnh, lnl, C, wf1h + l * SET1, wf1l + l * SET1, C, fc1b + l * C,
        nullptr, 0, x1h, x1l, M, 0, 0, 3, 16);
    // fcb = lrelu(flip(xfc1) @ fc2_w^T + b) -> fp32 (XCD-chunked)
    mgemm_k<1, true, true, false, false, true><<<384, 256, 0, stream>>>(
        x1h, x1l, C, wf2h + l * SET1, wf2l + l * SET1, C, fc2b_ + l * C, fcb,
        C, nullptr, nullptr, M, 0, 0, 3, 16);
    // dir1 (backward) first -> bm; dir0 last fuses combine into x.
    for (int di = 0; di < 2; di++) {
      const int dir = 1 - di;
      size_t wo = (size_t)(l * 2 + dir);
      for (int h = 0; h < 2; h++) {
        const int roff = h * MH;
        // in_proj -> xz_h (XCD-chunked: nt=12, mpx=8, grid 768)
        if (dir == 0)
          mgemm_k<0, false, false, false, false, true><<<768, 256, 0, stream>>>(
              x1h, x1l, C, winh + wo * SETI, winl + wo * SETI, 2 * DI, nullptr,
              xz_h, XZdim, nullptr, nullptr, MH, roff, 0, 12, 8);
        else
          mgemm_k<0, false, true, false, false, true><<<768, 256, 0, stream>>>(
              x1h, x1l, C, winh + wo * SETI, winl + wo * SETI, 2 * DI, nullptr,
              xz_h, XZdim, nullptr, nullptr, MH, roff, 0, 12, 8);
        // causal depthwise conv + silu -> xc planes (8-t quad)
        conv_k<<<(HB * NQ8 * (DI / 2)) / 256, 256, 0, stream>>>(
            xz_h, cw + wo * DI * DCONV, cb + wo * DI, xch, xcl);
        // x_proj -> fp32 [dt_r|B|C] rows (stride 64); MT=16 tiles
        mgemm64_k<0, false, 16><<<dim3(1, MH / 16), 256, 0, stream>>>(
            xch, xcl, DI, DI, wxh + wo * SETX, wxl + wo * SETX, ND, nullptr,
            xdbc, 64, nullptr, nullptr, MH, 0, 0, 0);
        // chunked selective scan (dt inline, reg-resident dtw) -> y planes
        scan_p1_k<<<dim3(3, NCHUNK, HB), 256, 0, stream>>>(
            xch, xcl, xdbc, dtw + wo * DI * DTR, dtb + wo * DI,
            alog + wo * DI * DSTATE, hchk, sdtb);
        scan_p2_k<<<(HB * DSTATE * DI) / 256, 256, 0, stream>>>(
            hchk, sdtb, alog + wo * DI * DSTATE);
        scan_p3_k<<<dim3(3, NCHUNK, HB), 256, 0, stream>>>(
            xz_h, xch, xcl, xdbc, dtw + wo * DI * DTR, dtb + wo * DI,
            alog + wo * DI * DSTATE, Dp + wo * DI, hchk, yh, yl);
        // out_proj (64^2, XCD-chunked: nt=6, mpx=16, grid 768)
        if (dir == 1)
          mgemm64_k<0, false, 64, true><<<768, 256, 0, stream>>>(
              yh, yl, DI, DI, wowh + wo * SETO, wowl + wo * SETO, C, nullptr,
              bm, C, nullptr, nullptr, MH, roff, 6, 16);
        else
          mgemm64_k<4, false, 64, true><<<768, 256, 0, stream>>>(
              yh, yl, DI, DI, wowh + wo * SETO, wowl + wo * SETO, C, nullptr,
              x, C, fcb, bm, MH, roff, 6, 16);
      }
    }
  }
  ln_stats2_k<<<M / 4, 256, 0, stream>>>(x, stats2);
  ln_scatter_k<<<241, 256, 0, stream>>>(x, stats2, lnfg, lnfb, out);
}